// Round 11
// baseline (580.354 us; speedup 1.0000x reference)
//
#include <hip/hip_runtime.h>

// Problem constants (match reference setup_inputs)
constexpr int N_NODES = 50000;
constexpr int N_EDGES = 800000;
constexpr int N_ETOT  = N_EDGES + N_NODES;   // with self loops
constexpr int HID     = 128;
constexpr int HEADS   = 4;
constexpr int ED      = 12;
constexpr int LAYERS  = 4;
constexpr float BN_EPS = 1e-5f;
constexpr int EB = (N_ETOT + 255) / 256;          // 3321 edge blocks
constexpr int GB = (N_NODES + 63) / 64;           // 782 gemm blocks (MFMA kernels)
constexpr int GBH = (N_NODES + 31) / 32;          // 1563 gemm0 blocks (32 rows each)
constexpr int WB = (LAYERS * HID * HID + 255) / 256;  // 256 packW blocks
constexpr int NODE_BLKS = (N_NODES + 3) / 4;          // 12500
// counting-sort CSR build (all-LDS atomics)
constexpr int CHUNK  = 2048;                          // edges per count/scatter block
constexpr int NCHUNK = (N_ETOT + CHUNK - 1) / CHUNK;  // 416
constexpr int NB     = (N_NODES + 127) / 128;         // 391 coarse buckets (dst>>7)
constexpr int F_TOT  = NB * NCHUNK;                   // 162656 flattened (bucket,chunk)
constexpr int SB3    = (F_TOT + 255) / 256;           // 636 scan blocks

typedef __attribute__((ext_vector_type(8))) short short8;
typedef __attribute__((ext_vector_type(4))) float floatx4;

__device__ inline unsigned bf16pair(float a, float b) {
    unsigned ua = __float_as_uint(a), ub = __float_as_uint(b);
    ua = (ua + 0x7FFFu + ((ua >> 16) & 1u)) >> 16;
    ub = (ub + 0x7FFFu + ((ub >> 16) & 1u)) >> 16;
    return ua | (ub << 16);
}

// ---------------------------------------------------------------------------
// pre1: [gemm0 | countA | eamean | packW] — all independent. gemm0 now does
// 32 rows/block (1563 blocks, was 782x64): the dispatch was grid-parallelism
// limited (3 waves/SIMD, occupancy 21% despite LDS/VGPR headroom — round 10).
// Wp tile staged as bf16 (16KB). Do NOT reintroduce two-half K staging
// (spilled, round 3); A-prefetch null (round 6); NT hints regress (round 9).
// ---------------------------------------------------------------------------
__launch_bounds__(256)
__global__ void pre1_kernel(const int* __restrict__ dst, int* __restrict__ counts,
                            const float* __restrict__ ea, float* __restrict__ easum,
                            const float* __restrict__ W, unsigned short* __restrict__ wb,
                            const float* __restrict__ A, const float* __restrict__ B,
                            const float* __restrict__ bias, float* __restrict__ C,
                            unsigned* __restrict__ Cb) {
    __shared__ float smem[32 * 128];   // 16KB: gemm0 bf16 Bs; countA NB ints; eamean 12 f
    int bid = blockIdx.x, t = threadIdx.x;
    if (bid < GBH) {
        // ---- gemm0: h = relu(x @ Wp + bp), dual f32/bf16 out, 32 rows/block ----
        constexpr int K = 64;
        const float4* B4 = (const float4*)B;
        uint2* Bs2 = (uint2*)smem;   // element (k,c) = bf16 at u32 index k*64 + c/2
#pragma unroll
        for (int i = t; i < K * 32; i += 256) {
            float4 f = B4[i];
            Bs2[i] = make_uint2(bf16pair(f.x, f.y), bf16pair(f.z, f.w));
        }
        __syncthreads();

        int c0 = (t & 15) * 8;
        int r0 = (t >> 4) * 2;
        int rbase = bid * 32 + r0;

        float acc[2][8];
#pragma unroll
        for (int j = 0; j < 2; j++)
#pragma unroll
            for (int c = 0; c < 8; c++) acc[j][c] = 0.f;

        const float4* A4 = (const float4*)A;
        int rg[2];
#pragma unroll
        for (int j = 0; j < 2; j++) rg[j] = min(rbase + j, N_NODES - 1);

        const uint4* BsU = (const uint4*)smem;
        for (int kk = 0; kk < K; kk += 4) {
            float4 av[2];
#pragma unroll
            for (int j = 0; j < 2; j++) av[j] = A4[(size_t)rg[j] * (K / 4) + (kk >> 2)];
            float a_arr[2][4];
#pragma unroll
            for (int j = 0; j < 2; j++) {
                a_arr[j][0] = av[j].x; a_arr[j][1] = av[j].y;
                a_arr[j][2] = av[j].z; a_arr[j][3] = av[j].w;
            }
#pragma unroll
            for (int jj = 0; jj < 4; jj++) {
                uint4 bu = BsU[(kk + jj) * 16 + (c0 >> 3)];
                float b[8];
                b[0] = __uint_as_float(bu.x << 16);
                b[1] = __uint_as_float(bu.x & 0xFFFF0000u);
                b[2] = __uint_as_float(bu.y << 16);
                b[3] = __uint_as_float(bu.y & 0xFFFF0000u);
                b[4] = __uint_as_float(bu.z << 16);
                b[5] = __uint_as_float(bu.z & 0xFFFF0000u);
                b[6] = __uint_as_float(bu.w << 16);
                b[7] = __uint_as_float(bu.w & 0xFFFF0000u);
#pragma unroll
                for (int j = 0; j < 2; j++) {
                    float a = a_arr[j][jj];
#pragma unroll
                    for (int c = 0; c < 8; c++) acc[j][c] += a * b[c];
                }
            }
        }

#pragma unroll
        for (int j = 0; j < 2; j++) {
            int r = rbase + j;
            if (r < N_NODES) {
                float o[8];
#pragma unroll
                for (int c = 0; c < 8; c++) o[c] = fmaxf(acc[j][c] + bias[c0 + c], 0.f);
                ((float4*)(C + (size_t)r * 128 + c0))[0] = make_float4(o[0], o[1], o[2], o[3]);
                ((float4*)(C + (size_t)r * 128 + c0 + 4))[0] = make_float4(o[4], o[5], o[6], o[7]);
                uint4 pk;
                pk.x = bf16pair(o[0], o[1]); pk.y = bf16pair(o[2], o[3]);
                pk.z = bf16pair(o[4], o[5]); pk.w = bf16pair(o[6], o[7]);
                ((uint4*)(Cb + (size_t)r * 64 + (c0 >> 1)))[0] = pk;
            }
        }
    } else if (bid < GBH + NCHUNK) {
        // ---- countA: LDS histogram of coarse bucket (dst>>7) for one chunk ----
        int chunk = bid - GBH;
        int* lh = (int*)smem;
        for (int i = t; i < NB; i += 256) lh[i] = 0;
        __syncthreads();
        int e0 = chunk * CHUNK;
        int eend = min(e0 + CHUNK, N_ETOT);
        for (int e = e0 + t; e < eend; e += 256) {
            int d = (e < N_EDGES) ? dst[e] : (e - N_EDGES);
            atomicAdd(&lh[d >> 7], 1);
        }
        __syncthreads();
        for (int i = t; i < NB; i += 256) counts[(size_t)chunk * NB + i] = lh[i];
    } else if (bid < GBH + NCHUNK + 256) {
        int b2 = bid - GBH - NCHUNK;
        float* ls = smem;
        if (t < 12) ls[t] = 0.f;
        __syncthreads();
        float loc[12];
#pragma unroll
        for (int d = 0; d < 12; d++) loc[d] = 0.f;
        for (int e = b2 * 256 + t; e < N_EDGES; e += 256 * 256) {
            const float* er = ea + (size_t)e * ED;
#pragma unroll
            for (int d = 0; d < 12; d++) loc[d] += er[d];
        }
#pragma unroll
        for (int d = 0; d < 12; d++) atomicAdd(&ls[d], loc[d]);
        __syncthreads();
        if (t < 12) atomicAdd(&easum[t], ls[t]);
    } else {
        int idx = (bid - GBH - NCHUNK - 256) * 256 + t;
        if (idx < LAYERS * HID * HID) {
            int l = idx >> 14;
            int k = (idx >> 7) & 127;
            int n = idx & 127;
            unsigned u = __float_as_uint(W[idx]);
            u = (u + 0x7FFFu + ((u >> 16) & 1u)) >> 16;
            int kt = k >> 5, q = (k & 31) >> 3, j = k & 7;
            int nt = n >> 4, c = n & 15;
            int lane = q * 16 + c;
            wb[(size_t)l * 16384 + ((size_t)(kt * 8 + nt) * 64 + lane) * 8 + j] =
                (unsigned short)u;
        }
    }
}

// blocksum over flattened (bucket-major) count matrix: j = b*NCHUNK + c,
// stored as counts[c*NB + b].
__global__ void blocksum2_kernel(const int* __restrict__ counts, int* __restrict__ bsum) {
    __shared__ int sd[256];
    int t = threadIdx.x;
    int j = blockIdx.x * 256 + t;
    int v = 0;
    if (j < F_TOT) {
        int bb = j / NCHUNK, cc = j - bb * NCHUNK;
        v = counts[(size_t)cc * NB + bb];
    }
    sd[t] = v;
    __syncthreads();
#pragma unroll
    for (int off = 128; off; off >>= 1) {
        if (t < off) sd[t] += sd[t + off];
        __syncthreads();
    }
    if (t == 0) bsum[blockIdx.x] = sd[0];
}

// ---------------------------------------------------------------------------
// pre2: [bscan | prep] — block 0 scans SB3=636 block sums (3/thread) and
// writes sentinels; block 1 folds We/att_edge.
// ---------------------------------------------------------------------------
__launch_bounds__(256)
__global__ void pre2_kernel(const int* __restrict__ bsum, int* __restrict__ boff,
                            int* __restrict__ chunkbase, int* __restrict__ rowp,
                            const float* __restrict__ easum,
                            const float* __restrict__ We, const float* __restrict__ att_edge,
                            float* __restrict__ wea_all, float* __restrict__ aloop) {
    int t = threadIdx.x;
    if (blockIdx.x == 0) {
        __shared__ int sd[256];
        int b = 3 * t;
        int v0 = (b + 0 < SB3) ? bsum[b + 0] : 0;
        int v1 = (b + 1 < SB3) ? bsum[b + 1] : 0;
        int v2 = (b + 2 < SB3) ? bsum[b + 2] : 0;
        int tot = v0 + v1 + v2;
        sd[t] = tot;
        __syncthreads();
#pragma unroll
        for (int off = 1; off < 256; off <<= 1) {
            int u = (t >= off) ? sd[t - off] : 0;
            __syncthreads();
            sd[t] += u;
            __syncthreads();
        }
        int excl = sd[t] - tot;
        if (b + 0 < SB3) boff[b + 0] = excl;
        if (b + 1 < SB3) boff[b + 1] = excl + v0;
        if (b + 2 < SB3) boff[b + 2] = excl + v0 + v1;
        if (t == 255) {
            chunkbase[F_TOT] = sd[255];    // == N_ETOT
            rowp[N_NODES] = N_ETOT;
        }
    } else {
        __shared__ float em[12];
        __shared__ float weash[LAYERS * ED * HEADS];
        if (t < 12) em[t] = easum[t] / (float)N_EDGES;
        if (t < LAYERS * ED * HEADS) {
            int l = t / (ED * HEADS);
            int r = t % (ED * HEADS);
            int d = r / HEADS;
            int h = r % HEADS;
            float sum = 0.f;
#pragma unroll
            for (int c = 0; c < 32; c++)
                sum += We[((size_t)(l * ED + d)) * HID + h * 32 + c] *
                       att_edge[(l * HEADS + h) * 32 + c];
            wea_all[t] = sum;
            weash[t] = sum;
        }
        __syncthreads();
        if (t < LAYERS * HEADS) {
            int l = t / HEADS, h = t % HEADS;
            float s = 0.f;
#pragma unroll
            for (int d = 0; d < 12; d++) s += em[d] * weash[l * ED * HEADS + d * HEADS + h];
            aloop[t] = s;
        }
    }
}

// add-back: chunkbase[j] = exclusive scan of translated counts
__global__ void addback_kernel(const int* __restrict__ counts, const int* __restrict__ boff,
                               int* __restrict__ chunkbase) {
    __shared__ int sd[256];
    int t = threadIdx.x;
    int j = blockIdx.x * 256 + t;
    int v = 0;
    if (j < F_TOT) {
        int bb = j / NCHUNK, cc = j - bb * NCHUNK;
        v = counts[(size_t)cc * NB + bb];
    }
    sd[t] = v;
    __syncthreads();
#pragma unroll
    for (int off = 1; off < 256; off <<= 1) {
        int u = (t >= off) ? sd[t - off] : 0;
        __syncthreads();
        sd[t] += u;
        __syncthreads();
    }
    if (j < F_TOT) chunkbase[j] = sd[t] - v + boff[blockIdx.x];
}

// ---------------------------------------------------------------------------
// pre3: [xp-proj MFMA (layer 0) | scatterC]. scatterC: LDS-ranked partition
// into coarse-bucket regions; writes are ~NB short contiguous streams/block.
// ---------------------------------------------------------------------------
__launch_bounds__(256)
__global__ void pre3_kernel(const unsigned short* __restrict__ hAb,
                            const unsigned short* __restrict__ wb,
                            const float* __restrict__ att_s, const float* __restrict__ att_d,
                            unsigned* __restrict__ xpb,
                            float* __restrict__ asrc, float* __restrict__ adst,
                            const int* __restrict__ src, const int* __restrict__ dst,
                            const int* __restrict__ chunkbase, int2* __restrict__ bucketed) {
    __shared__ float smem[4 * 16 * 129];   // 33 KB
    int t = threadIdx.x;
    if (blockIdx.x >= GB) {
        int chunk = blockIdx.x - GB;
        int* lb = (int*)smem;       // NB bases
        int* lh = lb + NB;          // NB cursors
        for (int i = t; i < NB; i += 256) {
            lb[i] = chunkbase[(size_t)i * NCHUNK + chunk];
            lh[i] = 0;
        }
        __syncthreads();
        int e0 = chunk * CHUNK;
        int eend = min(e0 + CHUNK, N_ETOT);
        for (int e = e0 + t; e < eend; e += 256) {
            int s, d;
            if (e < N_EDGES) { s = src[e]; d = dst[e]; }
            else             { s = d = e - N_EDGES; }
            int b = d >> 7;
            int lr = atomicAdd(&lh[b], 1);
            bucketed[lb[b] + lr] = make_int2(s, e | ((d & 127) << 20));
        }
        return;
    }
    // ---- plain MFMA projection (layer 0), A from hAb ----
    int bid = blockIdx.x;
    float (*lds)[16][129] = (float (*)[16][129])smem;
    int w = t >> 6, lane = t & 63;
    int rbase = bid * 64 + w * 16;
    int mrow = lane & 15, quad = lane >> 4;

    floatx4 acc[8];
#pragma unroll
    for (int nt = 0; nt < 8; nt++) acc[nt] = (floatx4){0.f, 0.f, 0.f, 0.f};

    int arow = min(rbase + mrow, N_NODES - 1);
    const short8* wb8 = (const short8*)wb;
#pragma unroll
    for (int kt = 0; kt < 4; kt++) {
        short8 afrag = *(const short8*)(hAb + (size_t)arow * 128 + kt * 32 + quad * 8);
#pragma unroll
        for (int nt = 0; nt < 8; nt++) {
            short8 bfrag = wb8[(kt * 8 + nt) * 64 + lane];
            acc[nt] = __builtin_amdgcn_mfma_f32_16x16x32_bf16(afrag, bfrag, acc[nt], 0, 0, 0);
        }
    }
#pragma unroll
    for (int nt = 0; nt < 8; nt++)
#pragma unroll
        for (int rr = 0; rr < 4; rr++)
            lds[w][quad * 4 + rr][nt * 16 + mrow] = acc[nt][rr];

    int row = lane >> 2, h = lane & 3;
    int r = rbase + row;
    float vals[32];
    float ps = 0.f, pd = 0.f;
#pragma unroll
    for (int c = 0; c < 32; c++) {
        float v = lds[w][row][h * 32 + c];
        vals[c] = v;
        ps += v * att_s[h * 32 + c];
        pd += v * att_d[h * 32 + c];
    }
    if (r < N_NODES) {
        unsigned* dstp = xpb + (size_t)r * 64 + h * 16;
#pragma unroll
        for (int qq = 0; qq < 4; qq++) {
            uint4 o;
            o.x = bf16pair(vals[qq * 8 + 0], vals[qq * 8 + 1]);
            o.y = bf16pair(vals[qq * 8 + 2], vals[qq * 8 + 3]);
            o.z = bf16pair(vals[qq * 8 + 4], vals[qq * 8 + 5]);
            o.w = bf16pair(vals[qq * 8 + 6], vals[qq * 8 + 7]);
            ((uint4*)dstp)[qq] = o;
        }
        asrc[r * 4 + h] = ps;
        adst[r * 4 + h] = pd;
    }
}

// ---------------------------------------------------------------------------
// csrd: per-bucket CSR finalize. 128-bin LDS histogram + scan -> rowp; scatter
// bucket edges into final csr (contiguous 17KB window, L2-local).
// ---------------------------------------------------------------------------
__launch_bounds__(256)
__global__ void csrd_kernel(const int2* __restrict__ bucketed, const int* __restrict__ chunkbase,
                            int2* __restrict__ csr, int* __restrict__ rowp) {
    __shared__ int hist[128], exc[128], cur[128];
    int b = blockIdx.x, t = threadIdx.x;
    int base = chunkbase[(size_t)b * NCHUNK];
    int cend = chunkbase[(size_t)(b + 1) * NCHUNK];
    int cnt = cend - base;
    if (t < 128) { hist[t] = 0; cur[t] = 0; }
    __syncthreads();
    for (int i = t; i < cnt; i += 256)
        atomicAdd(&hist[(bucketed[base + i].y >> 20) & 127], 1);
    __syncthreads();
    if (t < 128) exc[t] = hist[t];
    __syncthreads();
#pragma unroll
    for (int off = 1; off < 128; off <<= 1) {
        int u = (t < 128 && t >= off) ? exc[t - off] : 0;
        __syncthreads();
        if (t < 128) exc[t] += u;
        __syncthreads();
    }
    if (t < 128) {
        exc[t] -= hist[t];   // exclusive
        int node = b * 128 + t;
        if (node < N_NODES) rowp[node] = base + exc[t];
    }
    __syncthreads();
    for (int i = t; i < cnt; i += 256) {
        int2 r = bucketed[base + i];
        int dl = (r.y >> 20) & 127;
        int lr = atomicAdd(&cur[dl], 1);
        csr[base + exc[dl] + lr] = make_int2(r.x, r.y & 0xFFFFF);
    }
}

// ---------------------------------------------------------------------------
// pre4: aedgep — per-edge attention terms for all layers in CSR order (bf16x4).
// ---------------------------------------------------------------------------
__launch_bounds__(256)
__global__ void pre4_kernel(const int2* __restrict__ csr, const float* __restrict__ ea,
                            const float* __restrict__ wea_all, const float* __restrict__ aloop,
                            uint2* __restrict__ aecsr) {
    __shared__ float wsh[LAYERS * ED * HEADS];
    __shared__ float lsh[LAYERS * HEADS];
    int t = threadIdx.x;
    if (t < LAYERS * ED * HEADS) wsh[t] = wea_all[t];
    if (t < LAYERS * HEADS) lsh[t] = aloop[t];
    __syncthreads();
    int i = blockIdx.x * 256 + t;
    if (i >= N_ETOT) return;
    int e = csr[i].y;
    float a[LAYERS][4];
    if (e < N_EDGES) {
        float er[12];
        const float* ep = ea + (size_t)e * ED;
#pragma unroll
        for (int d = 0; d < 12; d++) er[d] = ep[d];
#pragma unroll
        for (int l = 0; l < LAYERS; l++)
#pragma unroll
            for (int h = 0; h < 4; h++) {
                float s = 0.f;
#pragma unroll
                for (int d = 0; d < 12; d++) s += er[d] * wsh[l * 48 + d * 4 + h];
                a[l][h] = s;
            }
    } else {
#pragma unroll
        for (int l = 0; l < LAYERS; l++)
#pragma unroll
            for (int h = 0; h < 4; h++) a[l][h] = lsh[l * 4 + h];
    }
#pragma unroll
    for (int l = 0; l < LAYERS; l++)
        aecsr[(size_t)l * N_ETOT + i] =
            make_uint2(bf16pair(a[l][0], a[l][1]), bf16pair(a[l][2], a[l][3]));
}

// ---------------------------------------------------------------------------
// Fused BN-update + MFMA projection (layers 1..3).
// ---------------------------------------------------------------------------
template <int ADD>
__launch_bounds__(256)
__global__ void gemm_fused_kernel(const float* __restrict__ outb,
                                  const float* __restrict__ bnsum,
                                  const float* __restrict__ bnsum2,
                                  const float* __restrict__ gamma,
                                  const float* __restrict__ beta,
                                  float* __restrict__ hA,
                                  const unsigned short* __restrict__ wb,
                                  const float* __restrict__ att_s,
                                  const float* __restrict__ att_d,
                                  unsigned* __restrict__ xpb,
                                  float* __restrict__ asrc, float* __restrict__ adst) {
    __shared__ float lds[4][16][129];
    __shared__ float sc_s[128], sh_s[128];
    int t = threadIdx.x;
    if (t < 128) {
        float mu = bnsum[t] / (float)N_NODES;
        float var = bnsum2[t] / (float)N_NODES - mu * mu;
        float inv = rsqrtf(var + BN_EPS);
        float g = gamma[t] * inv;
        sc_s[t] = g;
        sh_s[t] = beta[t] - mu * g;
    }
    __syncthreads();

    int w = t >> 6, lane = t & 63;
    int rbase = blockIdx.x * 64 + w * 16;
    int mrow = lane & 15, quad = lane >> 4;
    int arow = rbase + mrow;
    bool owner = arow < N_NODES;
    int ar = min(arow, N_NODES - 1);

    floatx4 acc[8];
#pragma unroll
    for (int nt = 0; nt < 8; nt++) acc[nt] = (floatx4){0.f, 0.f, 0.f, 0.f};

    const short8* wb8 = (const short8*)wb;
#pragma unroll
    for (int kt = 0; kt < 4; kt++) {
        int cb = kt * 32 + quad * 8;
        const float4* ob = (const float4*)(outb + (size_t)ar * 128 + cb);
        float4 o0 = ob[0], o1 = ob[1];
        float v[8];
        v[0] = fmaxf(o0.x * sc_s[cb + 0] + sh_s[cb + 0], 0.f);
        v[1] = fmaxf(o0.y * sc_s[cb + 1] + sh_s[cb + 1], 0.f);
        v[2] = fmaxf(o0.z * sc_s[cb + 2] + sh_s[cb + 2], 0.f);
        v[3] = fmaxf(o0.w * sc_s[cb + 3] + sh_s[cb + 3], 0.f);
        v[4] = fmaxf(o1.x * sc_s[cb + 4] + sh_s[cb + 4], 0.f);
        v[5] = fmaxf(o1.y * sc_s[cb + 5] + sh_s[cb + 5], 0.f);
        v[6] = fmaxf(o1.z * sc_s[cb + 6] + sh_s[cb + 6], 0.f);
        v[7] = fmaxf(o1.w * sc_s[cb + 7] + sh_s[cb + 7], 0.f);
        if (ADD) {
            const float4* hp = (const float4*)(hA + (size_t)ar * 128 + cb);
            float4 h0 = hp[0], h1 = hp[1];
            v[0] += h0.x; v[1] += h0.y; v[2] += h0.z; v[3] += h0.w;
            v[4] += h1.x; v[5] += h1.y; v[6] += h1.z; v[7] += h1.w;
        }
        if (owner) {
            float4* hw = (float4*)(hA + (size_t)ar * 128 + cb);
            hw[0] = make_float4(v[0], v[1], v[2], v[3]);
            hw[1] = make_float4(v[4], v[5], v[6], v[7]);
        }
        uint4 pk;
        pk.x = bf16pair(v[0], v[1]); pk.y = bf16pair(v[2], v[3]);
        pk.z = bf16pair(v[4], v[5]); pk.w = bf16pair(v[6], v[7]);
        short8 afrag = *(short8*)&pk;
#pragma unroll
        for (int nt = 0; nt < 8; nt++) {
            short8 bfrag = wb8[(kt * 8 + nt) * 64 + lane];
            acc[nt] = __builtin_amdgcn_mfma_f32_16x16x32_bf16(afrag, bfrag, acc[nt], 0, 0, 0);
        }
    }

#pragma unroll
    for (int nt = 0; nt < 8; nt++)
#pragma unroll
        for (int rr = 0; rr < 4; rr++)
            lds[w][quad * 4 + rr][nt * 16 + mrow] = acc[nt][rr];

    int row = lane >> 2, h = lane & 3;
    int r = rbase + row;
    float vals[32];
    float ps = 0.f, pd = 0.f;
#pragma unroll
    for (int c = 0; c < 32; c++) {
        float v = lds[w][row][h * 32 + c];
        vals[c] = v;
        ps += v * att_s[h * 32 + c];
        pd += v * att_d[h * 32 + c];
    }
    if (r < N_NODES) {
        unsigned* dstp = xpb + (size_t)r * 64 + h * 16;
#pragma unroll
        for (int qq = 0; qq < 4; qq++) {
            uint4 o;
            o.x = bf16pair(vals[qq * 8 + 0], vals[qq * 8 + 1]);
            o.y = bf16pair(vals[qq * 8 + 2], vals[qq * 8 + 3]);
            o.z = bf16pair(vals[qq * 8 + 4], vals[qq * 8 + 5]);
            o.w = bf16pair(vals[qq * 8 + 6], vals[qq * 8 + 7]);
            ((uint4*)dstp)[qq] = o;
        }
        asrc[r * 4 + h] = ps;
        adst[r * 4 + h] = pd;
    }
}

// ---------------------------------------------------------------------------
// Single-pass aggregation, 8-lane subgroups, 16 ch/lane (round-5 structure,
// plain cached loads — NT hints measured −43us total in round 9).
// ---------------------------------------------------------------------------
__launch_bounds__(256)
__global__ void node_kernel(const uint2* __restrict__ aecsr, const float* __restrict__ asrc,
                            const float* __restrict__ adst, const int* __restrict__ rowp,
                            const int2* __restrict__ csr, const unsigned* __restrict__ xpb,
                            float* __restrict__ out) {
    int gw = (blockIdx.x * blockDim.x + threadIdx.x) >> 6;
    int lane = threadIdx.x & 63;
    if (gw >= N_NODES) return;
    int sub = lane >> 3;
    int sl  = lane & 7;
    int h   = sl >> 1;
    int beg = rowp[gw], end = rowp[gw + 1];
    const uint4* xp4 = (const uint4*)xpb;
    float adh = adst[gw * 4 + h];

    float a[16];
#pragma unroll
    for (int c = 0; c < 16; c++) a[c] = 0.f;
    float den = 0.f;

#define PROC(JJ)                                                                 \
    {                                                                            \
        int2 se = csr[JJ];                                                       \
        uint2 ae = aecsr[JJ];                                                    \
        unsigned aw = (h & 2) ? ae.y : ae.x;                                     \
        float aeh = __uint_as_float((h & 1) ? (aw & 0xFFFF0000u) : (aw << 16));  \
        float ash = asrc[se.x * 4 + h];                                          \
        uint4 v0 = xp4[(size_t)se.x * 16 + sl * 2];                              \
        uint4 v1 = xp4[(size_t)se.x * 16 + sl * 2 + 1];                          \
        float lg = ash + adh + aeh;                                              \
        lg = (lg > 0.f) ? lg : 0.2f * lg;                                        \
        float ex = __expf(fminf(lg, 60.f));                                      \
        a[0]  += ex * __uint_as_float(v0.x << 16);                               \
        a[1]  += ex * __uint_as_float(v0.x & 0xFFFF0000u);                       \
        a[2]  += ex * __uint_as_float(v0.y << 16);                               \
        a[3]  += ex * __uint_as_float(v0.y & 0xFFFF0000u);                       \
        a[4]  += ex * __uint_as_float(v0.z << 16);                               \
        a[5]  += ex * __uint_as_float(v0.z & 0xFFFF0000u);                       \
        a[6]  += ex * __uint_as_float(v0.w << 16);                               \
        a[7]  += ex * __uint_as_float(v0.w & 0xFFFF0000u);                       \
        a[8]  += ex * __uint_as_float(v1.x << 16);                               \
        a[9]  += ex * __uint_as_float(v1.x & 0xFFFF0000u);                       \
        a[10] += ex * __uint_as_float(v1.y << 16);                               \
        a[11] += ex * __uint_as_float(v1.y & 0xFFFF0000u);                       \
        a[12] += ex * __uint_as_float(v1.z << 16);                               \
        a[13] += ex * __uint_as_float(v1.z & 0xFFFF0000u);                       \
        a[14] += ex * __uint_as_float(v1.w << 16);                               \
        a[15] += ex * __uint_as_float(v1.w & 0xFFFF0000u);                       \
        den += ex;                                                               \
    }

    int j = beg + sub;
    for (; j + 8 < end; j += 16) {
        PROC(j); PROC(j + 8);
    }
    for (; j < end; j += 8) PROC(j);
#undef PROC

#pragma unroll
    for (int c = 0; c < 16; c++) {
        a[c] += __shfl_xor(a[c], 8);
        a[c] += __shfl_xor(a[c], 16);
        a[c] += __shfl_xor(a[c], 32);
    }
    den += __shfl_xor(den, 8);
    den += __shfl_xor(den, 16);
    den += __shfl_xor(den, 32);
    float inv = 1.0f / den;
    if (sub == 0) {
        float* op = out + (size_t)gw * 128 + sl * 16;
        ((float4*)op)[0] = make_float4(a[0] * inv, a[1] * inv, a[2] * inv, a[3] * inv);
        ((float4*)op)[1] = make_float4(a[4] * inv, a[5] * inv, a[6] * inv, a[7] * inv);
        ((float4*)op)[2] = make_float4(a[8] * inv, a[9] * inv, a[10] * inv, a[11] * inv);
        ((float4*)op)[3] = make_float4(a[12] * inv, a[13] * inv, a[14] * inv, a[15] * inv);
    }
}

// ---------------------------------------------------------------------------
// BatchNorm statistics; final-layer standalone update (writes outp).
// ---------------------------------------------------------------------------
__launch_bounds__(256)
__global__ void bnstats_kernel(const float* __restrict__ h, float* __restrict__ bnsum,
                               float* __restrict__ bnsum2) {
    __shared__ float ls[256], ls2[256];
    int t = threadIdx.x;
    int c = t & 127, half = t >> 7;
    int r0 = blockIdx.x * 128;
    float s = 0.f, s2 = 0.f;
    int rend = min(r0 + 128, N_NODES);
    for (int r = r0 + half; r < rend; r += 2) {
        float v = h[(size_t)r * 128 + c];
        s += v; s2 += v * v;
    }
    ls[t] = s; ls2[t] = s2;
    __syncthreads();
    if (half == 0) {
        s += ls[t + 128]; s2 += ls2[t + 128];
        atomicAdd(&bnsum[c], s);
        atomicAdd(&bnsum2[c], s2);
    }
}

__launch_bounds__(256)
__global__ void finalupd_kernel(const float* __restrict__ outb, const float* __restrict__ bnsum,
                                const float* __restrict__ bnsum2, const float* __restrict__ gamma,
                                const float* __restrict__ beta, const float* __restrict__ hA,
                                float* __restrict__ dst) {
    __shared__ float sc_s[128], sh_s[128];
    int t = threadIdx.x;
    if (t < 128) {
        float mu = bnsum[t] / (float)N_NODES;
        float var = bnsum2[t] / (float)N_NODES - mu * mu;
        float inv = rsqrtf(var + BN_EPS);
        float g = gamma[t] * inv;
        sc_s[t] = g;
        sh_s[t] = beta[t] - mu * g;
    }
    __syncthreads();
    int i = blockIdx.x * blockDim.x + t;
    if (i >= N_NODES * 32) return;
    int c4 = (i & 31) * 4;
    float4 o = ((const float4*)outb)[i];
    float4 hh = ((const float4*)hA)[i];
    float4 v;
    v.x = fmaxf(o.x * sc_s[c4 + 0] + sh_s[c4 + 0], 0.f) + hh.x;
    v.y = fmaxf(o.y * sc_s[c4 + 1] + sh_s[c4 + 1], 0.f) + hh.y;
    v.z = fmaxf(o.z * sc_s[c4 + 2] + sh_s[c4 + 2], 0.f) + hh.z;
    v.w = fmaxf(o.w * sc_s[c4 + 3] + sh_s[c4 + 3], 0.f) + hh.w;
    ((float4*)dst)[i] = v;
}

// ---------------------------------------------------------------------------
extern "C" void kernel_launch(void* const* d_in, const int* in_sizes, int n_in,
                              void* d_out, int out_size, void* d_ws, size_t ws_size,
                              hipStream_t stream) {
    const float* x          = (const float*)d_in[0];
    const int*   edge_index = (const int*)d_in[1];
    const float* edge_attr  = (const float*)d_in[2];
    const float* Wp         = (const float*)d_in[3];
    const float* bp         = (const float*)d_in[4];
    const float* W          = (const float*)d_in[5];
    const float* We         = (const float*)d_in[6];
    const float* att_src    = (const float*)d_in[7];
    const float* att_dst    = (const float*)d_in[8];
    const float* att_edge   = (const float*)d_in[9];
    // d_in[10] bias: absorbed exactly by training-mode BN -> skipped
    const float* gamma      = (const float*)d_in[11];
    const float* beta       = (const float*)d_in[12];
    float* outp = (float*)d_out;

    const int* ei_src = edge_index;
    const int* ei_dst = edge_index + N_EDGES;

    char* p = (char*)d_ws;
    auto alloc = [&](size_t nbytes) {
        char* r = p;
        p += (nbytes + 255) & ~(size_t)255;
        return r;
    };
    // zero-initialized region: easum | bnsum(4 layers x 256)
    float* easum    = (float*)alloc(16 * 4);
    float* bnsumall = (float*)alloc((size_t)LAYERS * 256 * 4);
    size_t zero_bytes = (char*)(bnsumall + LAYERS * 256) - (char*)easum;

    float* hA       = (float*)alloc((size_t)N_NODES * 128 * 4);
    unsigned* hAb   = (unsigned*)alloc((size_t)N_NODES * 64 * 4);   // bf16x2 (layer-0 A feed)
    unsigned* xpb   = (unsigned*)alloc((size_t)N_NODES * 64 * 4);   // bf16x2 gather payload
    float* outb     = (float*)alloc((size_t)N_NODES * 128 * 4);
    float* asrc     = (float*)alloc((size_t)N_NODES * 4 * 4);
    float* adst     = (float*)alloc((size_t)N_NODES * 4 * 4);
    float* wea_all  = (float*)alloc((LAYERS * 48 + 16) * 4);
    float* aloop    = wea_all + LAYERS * 48;
    unsigned short* wb = (unsigned short*)alloc((size_t)LAYERS * 16384 * 2);
    int* rowp       = (int*)alloc(((size_t)N_NODES + 1) * 4);
    int* counts     = (int*)alloc((size_t)F_TOT * 4);
    int* chunkbase  = (int*)alloc(((size_t)F_TOT + 1) * 4);
    int2* bucketed  = (int2*)alloc((size_t)N_ETOT * 8);
    int2* csr       = (int2*)alloc((size_t)N_ETOT * 8);
    uint2* aecsr    = (uint2*)alloc((size_t)LAYERS * N_ETOT * 8);
    int* bsum       = (int*)alloc(1024 * 4);
    int* boff       = (int*)alloc(1024 * 4);

    (void)hipMemsetAsync(easum, 0, zero_bytes, stream);

    // ---- preamble: counting-sort CSR build + folded matrices + W pack + gemm0 ----
    pre1_kernel<<<GBH + NCHUNK + 256 + WB, 256, 0, stream>>>(
        ei_dst, counts, edge_attr, easum, W, wb, x, Wp, bp, hA, hAb);
    blocksum2_kernel<<<SB3, 256, 0, stream>>>(counts, bsum);
    pre2_kernel<<<2, 256, 0, stream>>>(bsum, boff, chunkbase, rowp, easum, We, att_edge,
                                       wea_all, aloop);
    addback_kernel<<<SB3, 256, 0, stream>>>(counts, boff, chunkbase);
    pre3_kernel<<<GB + NCHUNK, 256, 0, stream>>>(
        (const unsigned short*)hAb, wb, att_src, att_dst, xpb, asrc, adst,
        ei_src, ei_dst, chunkbase, bucketed);
    csrd_kernel<<<NB, 256, 0, stream>>>(bucketed, chunkbase, csr, rowp);
    pre4_kernel<<<EB, 256, 0, stream>>>(csr, edge_attr, wea_all, aloop, aecsr);

    for (int l = 0; l < LAYERS; l++) {
        float* bnsum  = bnsumall + l * 256;
        float* bnsum2 = bnsum + 128;
        node_kernel<<<NODE_BLKS, 256, 0, stream>>>(
            aecsr + (size_t)l * N_ETOT, asrc, adst, rowp, csr, xpb, outb);
        bnstats_kernel<<<(N_NODES + 127) / 128, 256, 0, stream>>>(outb, bnsum, bnsum2);
        if (l < LAYERS - 1) {
            // fused: h_{l+1} = relu(bn_l(outb)) (+ hA if l>0) -> hA, A-frag in-reg
            if (l == 0)
                gemm_fused_kernel<0><<<GB, 256, 0, stream>>>(
                    outb, bnsum, bnsum2, gamma + l * 128, beta + l * 128, hA,
                    wb + (size_t)(l + 1) * 16384, att_src + (l + 1) * 128,
                    att_dst + (l + 1) * 128, xpb, asrc, adst);
            else
                gemm_fused_kernel<1><<<GB, 256, 0, stream>>>(
                    outb, bnsum, bnsum2, gamma + l * 128, beta + l * 128, hA,
                    wb + (size_t)(l + 1) * 16384, att_src + (l + 1) * 128,
                    att_dst + (l + 1) * 128, xpb, asrc, adst);
        } else {
            finalupd_kernel<<<(N_NODES * 32 + 255) / 256, 256, 0, stream>>>(
                outb, bnsum, bnsum2, gamma + l * 128, beta + l * 128, hA, outp);
        }
    }
}

// Round 12
// 561.365 us; speedup vs baseline: 1.0338x; 1.0338x over previous
//
#include <hip/hip_runtime.h>

// Problem constants (match reference setup_inputs)
constexpr int N_NODES = 50000;
constexpr int N_EDGES = 800000;
constexpr int N_ETOT  = N_EDGES + N_NODES;   // with self loops
constexpr int HID     = 128;
constexpr int HEADS   = 4;
constexpr int ED      = 12;
constexpr int LAYERS  = 4;
constexpr float BN_EPS = 1e-5f;
constexpr int EB = (N_ETOT + 255) / 256;          // 3321 edge blocks
constexpr int GB = (N_NODES + 63) / 64;           // 782 gemm blocks
constexpr int WB = (LAYERS * HID * HID + 255) / 256;  // 256 packW blocks
constexpr int NODE_BLKS = (N_NODES + 3) / 4;          // 12500
// counting-sort CSR build (all-LDS atomics)
constexpr int CHUNK  = 2048;                          // edges per count/scatter block
constexpr int NCHUNK = (N_ETOT + CHUNK - 1) / CHUNK;  // 416
constexpr int NB     = (N_NODES + 127) / 128;         // 391 coarse buckets (dst>>7)
constexpr int F_TOT  = NB * NCHUNK;                   // 162656 flattened (bucket,chunk)
constexpr int SB3    = (F_TOT + 255) / 256;           // 636 scan blocks

typedef __attribute__((ext_vector_type(8))) short short8;
typedef __attribute__((ext_vector_type(4))) float floatx4;

__device__ inline unsigned bf16pair(float a, float b) {
    unsigned ua = __float_as_uint(a), ub = __float_as_uint(b);
    ua = (ua + 0x7FFFu + ((ua >> 16) & 1u)) >> 16;
    ub = (ub + 0x7FFFu + ((ub >> 16) & 1u)) >> 16;
    return ua | (ub << 16);
}

// ---------------------------------------------------------------------------
// pre1: [gemm0 | countA | eamean | packW] — round-5 proven form (f32 Bs,
// 64 rows/block, 52 VGPR). pre1 attempts that FAILED: two-half staging
// (spill, r3), A-prefetch (null, r6), bf16 Bs (null, r10), 32-row grid
// (regressed, r11) — this dispatch is at its structural floor; leave it.
// ---------------------------------------------------------------------------
__launch_bounds__(256)
__global__ void pre1_kernel(const int* __restrict__ dst, int* __restrict__ counts,
                            const float* __restrict__ ea, float* __restrict__ easum,
                            const float* __restrict__ W, unsigned short* __restrict__ wb,
                            const float* __restrict__ A, const float* __restrict__ B,
                            const float* __restrict__ bias, float* __restrict__ C,
                            unsigned* __restrict__ Cb) {
    __shared__ float smem[64 * 128];   // gemm0 Bs; countA uses NB ints; eamean 12 floats
    int bid = blockIdx.x, t = threadIdx.x;
    if (bid < GB) {
        // ---- gemm0: h = relu(x @ Wp + bp), dual f32/bf16 out ----
        constexpr int K = 64;
        const float4* B4 = (const float4*)B;
        float4* Bs4 = (float4*)smem;
#pragma unroll
        for (int i = t; i < K * 32; i += 256) Bs4[i] = B4[i];
        __syncthreads();

        int c0 = (t & 15) * 8;
        int r0 = (t >> 4) * 4;
        int rbase = bid * 64 + r0;

        float acc[4][8];
#pragma unroll
        for (int j = 0; j < 4; j++)
#pragma unroll
            for (int c = 0; c < 8; c++) acc[j][c] = 0.f;

        const float4* A4 = (const float4*)A;
        int rg[4];
#pragma unroll
        for (int j = 0; j < 4; j++) rg[j] = min(rbase + j, N_NODES - 1);

        for (int kk = 0; kk < K; kk += 4) {
            float4 av[4];
#pragma unroll
            for (int j = 0; j < 4; j++) av[j] = A4[(size_t)rg[j] * (K / 4) + (kk >> 2)];
            float a_arr[4][4];
#pragma unroll
            for (int j = 0; j < 4; j++) {
                a_arr[j][0] = av[j].x; a_arr[j][1] = av[j].y;
                a_arr[j][2] = av[j].z; a_arr[j][3] = av[j].w;
            }
#pragma unroll
            for (int jj = 0; jj < 4; jj++) {
                float4 b0 = Bs4[(kk + jj) * 32 + (c0 >> 2)];
                float4 b1 = Bs4[(kk + jj) * 32 + (c0 >> 2) + 1];
#pragma unroll
                for (int j = 0; j < 4; j++) {
                    float a = a_arr[j][jj];
                    acc[j][0] += a * b0.x; acc[j][1] += a * b0.y;
                    acc[j][2] += a * b0.z; acc[j][3] += a * b0.w;
                    acc[j][4] += a * b1.x; acc[j][5] += a * b1.y;
                    acc[j][6] += a * b1.z; acc[j][7] += a * b1.w;
                }
            }
        }

#pragma unroll
        for (int j = 0; j < 4; j++) {
            int r = rbase + j;
            if (r < N_NODES) {
                float o[8];
#pragma unroll
                for (int c = 0; c < 8; c++) o[c] = fmaxf(acc[j][c] + bias[c0 + c], 0.f);
                ((float4*)(C + (size_t)r * 128 + c0))[0] = make_float4(o[0], o[1], o[2], o[3]);
                ((float4*)(C + (size_t)r * 128 + c0 + 4))[0] = make_float4(o[4], o[5], o[6], o[7]);
                uint4 pk;
                pk.x = bf16pair(o[0], o[1]); pk.y = bf16pair(o[2], o[3]);
                pk.z = bf16pair(o[4], o[5]); pk.w = bf16pair(o[6], o[7]);
                ((uint4*)(Cb + (size_t)r * 64 + (c0 >> 1)))[0] = pk;
            }
        }
    } else if (bid < GB + NCHUNK) {
        // ---- countA: LDS histogram of coarse bucket (dst>>7) for one chunk ----
        int chunk = bid - GB;
        int* lh = (int*)smem;
        for (int i = t; i < NB; i += 256) lh[i] = 0;
        __syncthreads();
        int e0 = chunk * CHUNK;
        int eend = min(e0 + CHUNK, N_ETOT);
        for (int e = e0 + t; e < eend; e += 256) {
            int d = (e < N_EDGES) ? dst[e] : (e - N_EDGES);
            atomicAdd(&lh[d >> 7], 1);
        }
        __syncthreads();
        for (int i = t; i < NB; i += 256) counts[(size_t)chunk * NB + i] = lh[i];
    } else if (bid < GB + NCHUNK + 256) {
        int b2 = bid - GB - NCHUNK;
        float* ls = smem;
        if (t < 12) ls[t] = 0.f;
        __syncthreads();
        float loc[12];
#pragma unroll
        for (int d = 0; d < 12; d++) loc[d] = 0.f;
        for (int e = b2 * 256 + t; e < N_EDGES; e += 256 * 256) {
            const float* er = ea + (size_t)e * ED;
#pragma unroll
            for (int d = 0; d < 12; d++) loc[d] += er[d];
        }
#pragma unroll
        for (int d = 0; d < 12; d++) atomicAdd(&ls[d], loc[d]);
        __syncthreads();
        if (t < 12) atomicAdd(&easum[t], ls[t]);
    } else {
        int idx = (bid - GB - NCHUNK - 256) * 256 + t;
        if (idx < LAYERS * HID * HID) {
            int l = idx >> 14;
            int k = (idx >> 7) & 127;
            int n = idx & 127;
            unsigned u = __float_as_uint(W[idx]);
            u = (u + 0x7FFFu + ((u >> 16) & 1u)) >> 16;
            int kt = k >> 5, q = (k & 31) >> 3, j = k & 7;
            int nt = n >> 4, c = n & 15;
            int lane = q * 16 + c;
            wb[(size_t)l * 16384 + ((size_t)(kt * 8 + nt) * 64 + lane) * 8 + j] =
                (unsigned short)u;
        }
    }
}

// blocksum over flattened (bucket-major) count matrix: j = b*NCHUNK + c,
// stored as counts[c*NB + b].
__global__ void blocksum2_kernel(const int* __restrict__ counts, int* __restrict__ bsum) {
    __shared__ int sd[256];
    int t = threadIdx.x;
    int j = blockIdx.x * 256 + t;
    int v = 0;
    if (j < F_TOT) {
        int bb = j / NCHUNK, cc = j - bb * NCHUNK;
        v = counts[(size_t)cc * NB + bb];
    }
    sd[t] = v;
    __syncthreads();
#pragma unroll
    for (int off = 128; off; off >>= 1) {
        if (t < off) sd[t] += sd[t + off];
        __syncthreads();
    }
    if (t == 0) bsum[blockIdx.x] = sd[0];
}

// ---------------------------------------------------------------------------
// pre2: [bscan | prep] — block 0 scans SB3=636 block sums (3/thread) and
// writes sentinels; block 1 folds We/att_edge.
// ---------------------------------------------------------------------------
__launch_bounds__(256)
__global__ void pre2_kernel(const int* __restrict__ bsum, int* __restrict__ boff,
                            int* __restrict__ chunkbase, int* __restrict__ rowp,
                            const float* __restrict__ easum,
                            const float* __restrict__ We, const float* __restrict__ att_edge,
                            float* __restrict__ wea_all, float* __restrict__ aloop) {
    int t = threadIdx.x;
    if (blockIdx.x == 0) {
        __shared__ int sd[256];
        int b = 3 * t;
        int v0 = (b + 0 < SB3) ? bsum[b + 0] : 0;
        int v1 = (b + 1 < SB3) ? bsum[b + 1] : 0;
        int v2 = (b + 2 < SB3) ? bsum[b + 2] : 0;
        int tot = v0 + v1 + v2;
        sd[t] = tot;
        __syncthreads();
#pragma unroll
        for (int off = 1; off < 256; off <<= 1) {
            int u = (t >= off) ? sd[t - off] : 0;
            __syncthreads();
            sd[t] += u;
            __syncthreads();
        }
        int excl = sd[t] - tot;
        if (b + 0 < SB3) boff[b + 0] = excl;
        if (b + 1 < SB3) boff[b + 1] = excl + v0;
        if (b + 2 < SB3) boff[b + 2] = excl + v0 + v1;
        if (t == 255) {
            chunkbase[F_TOT] = sd[255];    // == N_ETOT
            rowp[N_NODES] = N_ETOT;
        }
    } else {
        __shared__ float em[12];
        __shared__ float weash[LAYERS * ED * HEADS];
        if (t < 12) em[t] = easum[t] / (float)N_EDGES;
        if (t < LAYERS * ED * HEADS) {
            int l = t / (ED * HEADS);
            int r = t % (ED * HEADS);
            int d = r / HEADS;
            int h = r % HEADS;
            float sum = 0.f;
#pragma unroll
            for (int c = 0; c < 32; c++)
                sum += We[((size_t)(l * ED + d)) * HID + h * 32 + c] *
                       att_edge[(l * HEADS + h) * 32 + c];
            wea_all[t] = sum;
            weash[t] = sum;
        }
        __syncthreads();
        if (t < LAYERS * HEADS) {
            int l = t / HEADS, h = t % HEADS;
            float s = 0.f;
#pragma unroll
            for (int d = 0; d < 12; d++) s += em[d] * weash[l * ED * HEADS + d * HEADS + h];
            aloop[t] = s;
        }
    }
}

// add-back: chunkbase[j] = exclusive scan of translated counts
__global__ void addback_kernel(const int* __restrict__ counts, const int* __restrict__ boff,
                               int* __restrict__ chunkbase) {
    __shared__ int sd[256];
    int t = threadIdx.x;
    int j = blockIdx.x * 256 + t;
    int v = 0;
    if (j < F_TOT) {
        int bb = j / NCHUNK, cc = j - bb * NCHUNK;
        v = counts[(size_t)cc * NB + bb];
    }
    sd[t] = v;
    __syncthreads();
#pragma unroll
    for (int off = 1; off < 256; off <<= 1) {
        int u = (t >= off) ? sd[t - off] : 0;
        __syncthreads();
        sd[t] += u;
        __syncthreads();
    }
    if (j < F_TOT) chunkbase[j] = sd[t] - v + boff[blockIdx.x];
}

// ---------------------------------------------------------------------------
// pre3: [xp-proj MFMA (layer 0) | scatterC]. scatterC: LDS-ranked partition
// into coarse-bucket regions; writes are ~NB short contiguous streams/block.
// ---------------------------------------------------------------------------
__launch_bounds__(256)
__global__ void pre3_kernel(const unsigned short* __restrict__ hAb,
                            const unsigned short* __restrict__ wb,
                            const float* __restrict__ att_s, const float* __restrict__ att_d,
                            unsigned* __restrict__ xpb,
                            float* __restrict__ asrc, float* __restrict__ adst,
                            const int* __restrict__ src, const int* __restrict__ dst,
                            const int* __restrict__ chunkbase, int2* __restrict__ bucketed) {
    __shared__ float smem[4 * 16 * 129];   // 33 KB
    int t = threadIdx.x;
    if (blockIdx.x >= GB) {
        int chunk = blockIdx.x - GB;
        int* lb = (int*)smem;       // NB bases
        int* lh = lb + NB;          // NB cursors
        for (int i = t; i < NB; i += 256) {
            lb[i] = chunkbase[(size_t)i * NCHUNK + chunk];
            lh[i] = 0;
        }
        __syncthreads();
        int e0 = chunk * CHUNK;
        int eend = min(e0 + CHUNK, N_ETOT);
        for (int e = e0 + t; e < eend; e += 256) {
            int s, d;
            if (e < N_EDGES) { s = src[e]; d = dst[e]; }
            else             { s = d = e - N_EDGES; }
            int b = d >> 7;
            int lr = atomicAdd(&lh[b], 1);
            bucketed[lb[b] + lr] = make_int2(s, e | ((d & 127) << 20));
        }
        return;
    }
    // ---- plain MFMA projection (layer 0), A from hAb ----
    int bid = blockIdx.x;
    float (*lds)[16][129] = (float (*)[16][129])smem;
    int w = t >> 6, lane = t & 63;
    int rbase = bid * 64 + w * 16;
    int mrow = lane & 15, quad = lane >> 4;

    floatx4 acc[8];
#pragma unroll
    for (int nt = 0; nt < 8; nt++) acc[nt] = (floatx4){0.f, 0.f, 0.f, 0.f};

    int arow = min(rbase + mrow, N_NODES - 1);
    const short8* wb8 = (const short8*)wb;
#pragma unroll
    for (int kt = 0; kt < 4; kt++) {
        short8 afrag = *(const short8*)(hAb + (size_t)arow * 128 + kt * 32 + quad * 8);
#pragma unroll
        for (int nt = 0; nt < 8; nt++) {
            short8 bfrag = wb8[(kt * 8 + nt) * 64 + lane];
            acc[nt] = __builtin_amdgcn_mfma_f32_16x16x32_bf16(afrag, bfrag, acc[nt], 0, 0, 0);
        }
    }
#pragma unroll
    for (int nt = 0; nt < 8; nt++)
#pragma unroll
        for (int rr = 0; rr < 4; rr++)
            lds[w][quad * 4 + rr][nt * 16 + mrow] = acc[nt][rr];

    int row = lane >> 2, h = lane & 3;
    int r = rbase + row;
    float vals[32];
    float ps = 0.f, pd = 0.f;
#pragma unroll
    for (int c = 0; c < 32; c++) {
        float v = lds[w][row][h * 32 + c];
        vals[c] = v;
        ps += v * att_s[h * 32 + c];
        pd += v * att_d[h * 32 + c];
    }
    if (r < N_NODES) {
        unsigned* dstp = xpb + (size_t)r * 64 + h * 16;
#pragma unroll
        for (int qq = 0; qq < 4; qq++) {
            uint4 o;
            o.x = bf16pair(vals[qq * 8 + 0], vals[qq * 8 + 1]);
            o.y = bf16pair(vals[qq * 8 + 2], vals[qq * 8 + 3]);
            o.z = bf16pair(vals[qq * 8 + 4], vals[qq * 8 + 5]);
            o.w = bf16pair(vals[qq * 8 + 6], vals[qq * 8 + 7]);
            ((uint4*)dstp)[qq] = o;
        }
        asrc[r * 4 + h] = ps;
        adst[r * 4 + h] = pd;
    }
}

// ---------------------------------------------------------------------------
// csrd: per-bucket CSR finalize. 128-bin LDS histogram + scan -> rowp; scatter
// bucket edges into final csr + u16 srcs (node reads only srcs: 2B vs 8B).
// ---------------------------------------------------------------------------
__launch_bounds__(256)
__global__ void csrd_kernel(const int2* __restrict__ bucketed, const int* __restrict__ chunkbase,
                            int2* __restrict__ csr, unsigned short* __restrict__ srcs,
                            int* __restrict__ rowp) {
    __shared__ int hist[128], exc[128], cur[128];
    int b = blockIdx.x, t = threadIdx.x;
    int base = chunkbase[(size_t)b * NCHUNK];
    int cend = chunkbase[(size_t)(b + 1) * NCHUNK];
    int cnt = cend - base;
    if (t < 128) { hist[t] = 0; cur[t] = 0; }
    __syncthreads();
    for (int i = t; i < cnt; i += 256)
        atomicAdd(&hist[(bucketed[base + i].y >> 20) & 127], 1);
    __syncthreads();
    if (t < 128) exc[t] = hist[t];
    __syncthreads();
#pragma unroll
    for (int off = 1; off < 128; off <<= 1) {
        int u = (t < 128 && t >= off) ? exc[t - off] : 0;
        __syncthreads();
        if (t < 128) exc[t] += u;
        __syncthreads();
    }
    if (t < 128) {
        exc[t] -= hist[t];   // exclusive
        int node = b * 128 + t;
        if (node < N_NODES) rowp[node] = base + exc[t];
    }
    __syncthreads();
    for (int i = t; i < cnt; i += 256) {
        int2 r = bucketed[base + i];
        int dl = (r.y >> 20) & 127;
        int lr = atomicAdd(&cur[dl], 1);
        int pos = base + exc[dl] + lr;
        csr[pos] = make_int2(r.x, r.y & 0xFFFFF);
        srcs[pos] = (unsigned short)r.x;
    }
}

// ---------------------------------------------------------------------------
// pre4: aedgep — per-edge attention terms for all layers in CSR order (bf16x4).
// ---------------------------------------------------------------------------
__launch_bounds__(256)
__global__ void pre4_kernel(const int2* __restrict__ csr, const float* __restrict__ ea,
                            const float* __restrict__ wea_all, const float* __restrict__ aloop,
                            uint2* __restrict__ aecsr) {
    __shared__ float wsh[LAYERS * ED * HEADS];
    __shared__ float lsh[LAYERS * HEADS];
    int t = threadIdx.x;
    if (t < LAYERS * ED * HEADS) wsh[t] = wea_all[t];
    if (t < LAYERS * HEADS) lsh[t] = aloop[t];
    __syncthreads();
    int i = blockIdx.x * 256 + t;
    if (i >= N_ETOT) return;
    int e = csr[i].y;
    float a[LAYERS][4];
    if (e < N_EDGES) {
        float er[12];
        const float* ep = ea + (size_t)e * ED;
#pragma unroll
        for (int d = 0; d < 12; d++) er[d] = ep[d];
#pragma unroll
        for (int l = 0; l < LAYERS; l++)
#pragma unroll
            for (int h = 0; h < 4; h++) {
                float s = 0.f;
#pragma unroll
                for (int d = 0; d < 12; d++) s += er[d] * wsh[l * 48 + d * 4 + h];
                a[l][h] = s;
            }
    } else {
#pragma unroll
        for (int l = 0; l < LAYERS; l++)
#pragma unroll
            for (int h = 0; h < 4; h++) a[l][h] = lsh[l * 4 + h];
    }
#pragma unroll
    for (int l = 0; l < LAYERS; l++)
        aecsr[(size_t)l * N_ETOT + i] =
            make_uint2(bf16pair(a[l][0], a[l][1]), bf16pair(a[l][2], a[l][3]));
}

// ---------------------------------------------------------------------------
// Fused BN-update + MFMA projection (layers 1..3). outb is now bf16 (u32
// pairs): one uint4 load per lane per kt instead of two float4s.
// ---------------------------------------------------------------------------
template <int ADD>
__launch_bounds__(256)
__global__ void gemm_fused_kernel(const unsigned* __restrict__ outb,
                                  const float* __restrict__ bnsum,
                                  const float* __restrict__ bnsum2,
                                  const float* __restrict__ gamma,
                                  const float* __restrict__ beta,
                                  float* __restrict__ hA,
                                  const unsigned short* __restrict__ wb,
                                  const float* __restrict__ att_s,
                                  const float* __restrict__ att_d,
                                  unsigned* __restrict__ xpb,
                                  float* __restrict__ asrc, float* __restrict__ adst) {
    __shared__ float lds[4][16][129];
    __shared__ float sc_s[128], sh_s[128];
    int t = threadIdx.x;
    if (t < 128) {
        float mu = bnsum[t] / (float)N_NODES;
        float var = bnsum2[t] / (float)N_NODES - mu * mu;
        float inv = rsqrtf(var + BN_EPS);
        float g = gamma[t] * inv;
        sc_s[t] = g;
        sh_s[t] = beta[t] - mu * g;
    }
    __syncthreads();

    int w = t >> 6, lane = t & 63;
    int rbase = blockIdx.x * 64 + w * 16;
    int mrow = lane & 15, quad = lane >> 4;
    int arow = rbase + mrow;
    bool owner = arow < N_NODES;
    int ar = min(arow, N_NODES - 1);

    floatx4 acc[8];
#pragma unroll
    for (int nt = 0; nt < 8; nt++) acc[nt] = (floatx4){0.f, 0.f, 0.f, 0.f};

    const short8* wb8 = (const short8*)wb;
#pragma unroll
    for (int kt = 0; kt < 4; kt++) {
        int cb = kt * 32 + quad * 8;
        uint4 u = *(const uint4*)(outb + (size_t)ar * 64 + (cb >> 1));
        float v[8];
        v[0] = __uint_as_float(u.x << 16);
        v[1] = __uint_as_float(u.x & 0xFFFF0000u);
        v[2] = __uint_as_float(u.y << 16);
        v[3] = __uint_as_float(u.y & 0xFFFF0000u);
        v[4] = __uint_as_float(u.z << 16);
        v[5] = __uint_as_float(u.z & 0xFFFF0000u);
        v[6] = __uint_as_float(u.w << 16);
        v[7] = __uint_as_float(u.w & 0xFFFF0000u);
#pragma unroll
        for (int c = 0; c < 8; c++)
            v[c] = fmaxf(v[c] * sc_s[cb + c] + sh_s[cb + c], 0.f);
        if (ADD) {
            const float4* hp = (const float4*)(hA + (size_t)ar * 128 + cb);
            float4 h0 = hp[0], h1 = hp[1];
            v[0] += h0.x; v[1] += h0.y; v[2] += h0.z; v[3] += h0.w;
            v[4] += h1.x; v[5] += h1.y; v[6] += h1.z; v[7] += h1.w;
        }
        if (owner) {
            float4* hw = (float4*)(hA + (size_t)ar * 128 + cb);
            hw[0] = make_float4(v[0], v[1], v[2], v[3]);
            hw[1] = make_float4(v[4], v[5], v[6], v[7]);
        }
        uint4 pk;
        pk.x = bf16pair(v[0], v[1]); pk.y = bf16pair(v[2], v[3]);
        pk.z = bf16pair(v[4], v[5]); pk.w = bf16pair(v[6], v[7]);
        short8 afrag = *(short8*)&pk;
#pragma unroll
        for (int nt = 0; nt < 8; nt++) {
            short8 bfrag = wb8[(kt * 8 + nt) * 64 + lane];
            acc[nt] = __builtin_amdgcn_mfma_f32_16x16x32_bf16(afrag, bfrag, acc[nt], 0, 0, 0);
        }
    }

#pragma unroll
    for (int nt = 0; nt < 8; nt++)
#pragma unroll
        for (int rr = 0; rr < 4; rr++)
            lds[w][quad * 4 + rr][nt * 16 + mrow] = acc[nt][rr];

    int row = lane >> 2, h = lane & 3;
    int r = rbase + row;
    float vals[32];
    float ps = 0.f, pd = 0.f;
#pragma unroll
    for (int c = 0; c < 32; c++) {
        float v = lds[w][row][h * 32 + c];
        vals[c] = v;
        ps += v * att_s[h * 32 + c];
        pd += v * att_d[h * 32 + c];
    }
    if (r < N_NODES) {
        unsigned* dstp = xpb + (size_t)r * 64 + h * 16;
#pragma unroll
        for (int qq = 0; qq < 4; qq++) {
            uint4 o;
            o.x = bf16pair(vals[qq * 8 + 0], vals[qq * 8 + 1]);
            o.y = bf16pair(vals[qq * 8 + 2], vals[qq * 8 + 3]);
            o.z = bf16pair(vals[qq * 8 + 4], vals[qq * 8 + 5]);
            o.w = bf16pair(vals[qq * 8 + 6], vals[qq * 8 + 7]);
            ((uint4*)dstp)[qq] = o;
        }
        asrc[r * 4 + h] = ps;
        adst[r * 4 + h] = pd;
    }
}

// ---------------------------------------------------------------------------
// Single-pass aggregation, 8-lane subgroups, 16 ch/lane (round-5 structure).
// Changes vs r5: src via u16 srcs (plain cached loads — NT measured -43us,
// r9); output written as bf16 (halves outb traffic for the 3 consumers).
// ---------------------------------------------------------------------------
__launch_bounds__(256)
__global__ void node_kernel(const uint2* __restrict__ aecsr, const float* __restrict__ asrc,
                            const float* __restrict__ adst, const int* __restrict__ rowp,
                            const unsigned short* __restrict__ srcs,
                            const unsigned* __restrict__ xpb,
                            unsigned* __restrict__ out) {
    int gw = (blockIdx.x * blockDim.x + threadIdx.x) >> 6;
    int lane = threadIdx.x & 63;
    if (gw >= N_NODES) return;
    int sub = lane >> 3;
    int sl  = lane & 7;
    int h   = sl >> 1;
    int beg = rowp[gw], end = rowp[gw + 1];
    const uint4* xp4 = (const uint4*)xpb;
    float adh = adst[gw * 4 + h];

    float a[16];
#pragma unroll
    for (int c = 0; c < 16; c++) a[c] = 0.f;
    float den = 0.f;

#define PROC(JJ)                                                                 \
    {                                                                            \
        int sx = (int)srcs[JJ];                                                  \
        uint2 ae = aecsr[JJ];                                                    \
        unsigned aw = (h & 2) ? ae.y : ae.x;                                     \
        float aeh = __uint_as_float((h & 1) ? (aw & 0xFFFF0000u) : (aw << 16));  \
        float ash = asrc[sx * 4 + h];                                            \
        uint4 v0 = xp4[(size_t)sx * 16 + sl * 2];                                \
        uint4 v1 = xp4[(size_t)sx * 16 + sl * 2 + 1];                            \
        float lg = ash + adh + aeh;                                              \
        lg = (lg > 0.f) ? lg : 0.2f * lg;                                        \
        float ex = __expf(fminf(lg, 60.f));                                      \
        a[0]  += ex * __uint_as_float(v0.x << 16);                               \
        a[1]  += ex * __uint_as_float(v0.x & 0xFFFF0000u);                       \
        a[2]  += ex * __uint_as_float(v0.y << 16);                               \
        a[3]  += ex * __uint_as_float(v0.y & 0xFFFF0000u);                       \
        a[4]  += ex * __uint_as_float(v0.z << 16);                               \
        a[5]  += ex * __uint_as_float(v0.z & 0xFFFF0000u);                       \
        a[6]  += ex * __uint_as_float(v0.w << 16);                               \
        a[7]  += ex * __uint_as_float(v0.w & 0xFFFF0000u);                       \
        a[8]  += ex * __uint_as_float(v1.x << 16);                               \
        a[9]  += ex * __uint_as_float(v1.x & 0xFFFF0000u);                       \
        a[10] += ex * __uint_as_float(v1.y << 16);                               \
        a[11] += ex * __uint_as_float(v1.y & 0xFFFF0000u);                       \
        a[12] += ex * __uint_as_float(v1.z << 16);                               \
        a[13] += ex * __uint_as_float(v1.z & 0xFFFF0000u);                       \
        a[14] += ex * __uint_as_float(v1.w << 16);                               \
        a[15] += ex * __uint_as_float(v1.w & 0xFFFF0000u);                       \
        den += ex;                                                               \
    }

    int j = beg + sub;
    for (; j + 8 < end; j += 16) {
        PROC(j); PROC(j + 8);
    }
    for (; j < end; j += 8) PROC(j);
#undef PROC

#pragma unroll
    for (int c = 0; c < 16; c++) {
        a[c] += __shfl_xor(a[c], 8);
        a[c] += __shfl_xor(a[c], 16);
        a[c] += __shfl_xor(a[c], 32);
    }
    den += __shfl_xor(den, 8);
    den += __shfl_xor(den, 16);
    den += __shfl_xor(den, 32);
    float inv = 1.0f / den;
    if (sub == 0) {
        unsigned* op = out + (size_t)gw * 64 + sl * 8;
        uint4 o0, o1;
        o0.x = bf16pair(a[0] * inv, a[1] * inv);
        o0.y = bf16pair(a[2] * inv, a[3] * inv);
        o0.z = bf16pair(a[4] * inv, a[5] * inv);
        o0.w = bf16pair(a[6] * inv, a[7] * inv);
        o1.x = bf16pair(a[8] * inv, a[9] * inv);
        o1.y = bf16pair(a[10] * inv, a[11] * inv);
        o1.z = bf16pair(a[12] * inv, a[13] * inv);
        o1.w = bf16pair(a[14] * inv, a[15] * inv);
        ((uint4*)op)[0] = o0;
        ((uint4*)op)[1] = o1;
    }
}

// ---------------------------------------------------------------------------
// BatchNorm statistics over bf16 outb (u32-pair loads, 2 ch/thread-word).
// ---------------------------------------------------------------------------
__launch_bounds__(256)
__global__ void bnstats_kernel(const unsigned* __restrict__ hb, float* __restrict__ bnsum,
                               float* __restrict__ bnsum2) {
    __shared__ float ls[4][128], ls2[4][128];
    int t = threadIdx.x;
    int w32 = t & 63, rowoff = t >> 6;
    int r0 = blockIdx.x * 128;
    float s0 = 0.f, s1 = 0.f, q0 = 0.f, q1 = 0.f;
    int rend = min(r0 + 128, N_NODES);
    for (int r = r0 + rowoff; r < rend; r += 4) {
        unsigned u = hb[(size_t)r * 64 + w32];
        float v0 = __uint_as_float(u << 16);
        float v1 = __uint_as_float(u & 0xFFFF0000u);
        s0 += v0; q0 += v0 * v0;
        s1 += v1; q1 += v1 * v1;
    }
    ls[rowoff][w32 * 2 + 0] = s0;  ls[rowoff][w32 * 2 + 1] = s1;
    ls2[rowoff][w32 * 2 + 0] = q0; ls2[rowoff][w32 * 2 + 1] = q1;
    __syncthreads();
    if (t < 128) {
        float s = ls[0][t] + ls[1][t] + ls[2][t] + ls[3][t];
        float q = ls2[0][t] + ls2[1][t] + ls2[2][t] + ls2[3][t];
        atomicAdd(&bnsum[t], s);
        atomicAdd(&bnsum2[t], q);
    }
}

__launch_bounds__(256)
__global__ void finalupd_kernel(const unsigned* __restrict__ outb, const float* __restrict__ bnsum,
                                const float* __restrict__ bnsum2, const float* __restrict__ gamma,
                                const float* __restrict__ beta, const float* __restrict__ hA,
                                float* __restrict__ dst) {
    __shared__ float sc_s[128], sh_s[128];
    int t = threadIdx.x;
    if (t < 128) {
        float mu = bnsum[t] / (float)N_NODES;
        float var = bnsum2[t] / (float)N_NODES - mu * mu;
        float inv = rsqrtf(var + BN_EPS);
        float g = gamma[t] * inv;
        sc_s[t] = g;
        sh_s[t] = beta[t] - mu * g;
    }
    __syncthreads();
    int i = blockIdx.x * blockDim.x + t;
    if (i >= N_NODES * 32) return;
    int c4 = (i & 31) * 4;
    uint2 u = ((const uint2*)outb)[i];   // u32 idx 2i == row*(64) + (i&31)*2
    float o0 = __uint_as_float(u.x << 16);
    float o1 = __uint_as_float(u.x & 0xFFFF0000u);
    float o2 = __uint_as_float(u.y << 16);
    float o3 = __uint_as_float(u.y & 0xFFFF0000u);
    float4 hh = ((const float4*)hA)[i];
    float4 v;
    v.x = fmaxf(o0 * sc_s[c4 + 0] + sh_s[c4 + 0], 0.f) + hh.x;
    v.y = fmaxf(o1 * sc_s[c4 + 1] + sh_s[c4 + 1], 0.f) + hh.y;
    v.z = fmaxf(o2 * sc_s[c4 + 2] + sh_s[c4 + 2], 0.f) + hh.z;
    v.w = fmaxf(o3 * sc_s[c4 + 3] + sh_s[c4 + 3], 0.f) + hh.w;
    ((float4*)dst)[i] = v;
}

// ---------------------------------------------------------------------------
extern "C" void kernel_launch(void* const* d_in, const int* in_sizes, int n_in,
                              void* d_out, int out_size, void* d_ws, size_t ws_size,
                              hipStream_t stream) {
    const float* x          = (const float*)d_in[0];
    const int*   edge_index = (const int*)d_in[1];
    const float* edge_attr  = (const float*)d_in[2];
    const float* Wp         = (const float*)d_in[3];
    const float* bp         = (const float*)d_in[4];
    const float* W          = (const float*)d_in[5];
    const float* We         = (const float*)d_in[6];
    const float* att_src    = (const float*)d_in[7];
    const float* att_dst    = (const float*)d_in[8];
    const float* att_edge   = (const float*)d_in[9];
    // d_in[10] bias: absorbed exactly by training-mode BN -> skipped
    const float* gamma      = (const float*)d_in[11];
    const float* beta       = (const float*)d_in[12];
    float* outp = (float*)d_out;

    const int* ei_src = edge_index;
    const int* ei_dst = edge_index + N_EDGES;

    char* p = (char*)d_ws;
    auto alloc = [&](size_t nbytes) {
        char* r = p;
        p += (nbytes + 255) & ~(size_t)255;
        return r;
    };
    // zero-initialized region: easum | bnsum(4 layers x 256)
    float* easum    = (float*)alloc(16 * 4);
    float* bnsumall = (float*)alloc((size_t)LAYERS * 256 * 4);
    size_t zero_bytes = (char*)(bnsumall + LAYERS * 256) - (char*)easum;

    float* hA       = (float*)alloc((size_t)N_NODES * 128 * 4);
    unsigned* hAb   = (unsigned*)alloc((size_t)N_NODES * 64 * 4);   // bf16x2 (layer-0 A feed)
    unsigned* xpb   = (unsigned*)alloc((size_t)N_NODES * 64 * 4);   // bf16x2 gather payload
    unsigned* outb  = (unsigned*)alloc((size_t)N_NODES * 64 * 4);   // bf16x2 aggregation out
    float* asrc     = (float*)alloc((size_t)N_NODES * 4 * 4);
    float* adst     = (float*)alloc((size_t)N_NODES * 4 * 4);
    float* wea_all  = (float*)alloc((LAYERS * 48 + 16) * 4);
    float* aloop    = wea_all + LAYERS * 48;
    unsigned short* wb = (unsigned short*)alloc((size_t)LAYERS * 16384 * 2);
    int* rowp       = (int*)alloc(((size_t)N_NODES + 1) * 4);
    int* counts     = (int*)alloc((size_t)F_TOT * 4);
    int* chunkbase  = (int*)alloc(((size_t)F_TOT + 1) * 4);
    int2* bucketed  = (int2*)alloc((size_t)N_ETOT * 8);
    int2* csr       = (int2*)alloc((size_t)N_ETOT * 8);
    unsigned short* srcs = (unsigned short*)alloc((size_t)N_ETOT * 2);
    uint2* aecsr    = (uint2*)alloc((size_t)LAYERS * N_ETOT * 8);
    int* bsum       = (int*)alloc(1024 * 4);
    int* boff       = (int*)alloc(1024 * 4);

    (void)hipMemsetAsync(easum, 0, zero_bytes, stream);

    // ---- preamble: counting-sort CSR build + folded matrices + W pack + gemm0 ----
    pre1_kernel<<<GB + NCHUNK + 256 + WB, 256, 0, stream>>>(
        ei_dst, counts, edge_attr, easum, W, wb, x, Wp, bp, hA, hAb);
    blocksum2_kernel<<<SB3, 256, 0, stream>>>(counts, bsum);
    pre2_kernel<<<2, 256, 0, stream>>>(bsum, boff, chunkbase, rowp, easum, We, att_edge,
                                       wea_all, aloop);
    addback_kernel<<<SB3, 256, 0, stream>>>(counts, boff, chunkbase);
    pre3_kernel<<<GB + NCHUNK, 256, 0, stream>>>(
        (const unsigned short*)hAb, wb, att_src, att_dst, xpb, asrc, adst,
        ei_src, ei_dst, chunkbase, bucketed);
    csrd_kernel<<<NB, 256, 0, stream>>>(bucketed, chunkbase, csr, srcs, rowp);
    pre4_kernel<<<EB, 256, 0, stream>>>(csr, edge_attr, wea_all, aloop, aecsr);

    for (int l = 0; l < LAYERS; l++) {
        float* bnsum  = bnsumall + l * 256;
        float* bnsum2 = bnsum + 128;
        node_kernel<<<NODE_BLKS, 256, 0, stream>>>(
            aecsr + (size_t)l * N_ETOT, asrc, adst, rowp, srcs, xpb, outb);
        bnstats_kernel<<<(N_NODES + 127) / 128, 256, 0, stream>>>(outb, bnsum, bnsum2);
        if (l < LAYERS - 1) {
            // fused: h_{l+1} = relu(bn_l(outb)) (+ hA if l>0) -> hA, A-frag in-reg
            if (l == 0)
                gemm_fused_kernel<0><<<GB, 256, 0, stream>>>(
                    outb, bnsum, bnsum2, gamma + l * 128, beta + l * 128, hA,
                    wb + (size_t)(l + 1) * 16384, att_src + (l + 1) * 128,
                    att_dst + (l + 1) * 128, xpb, asrc, adst);
            else
                gemm_fused_kernel<1><<<GB, 256, 0, stream>>>(
                    outb, bnsum, bnsum2, gamma + l * 128, beta + l * 128, hA,
                    wb + (size_t)(l + 1) * 16384, att_src + (l + 1) * 128,
                    att_dst + (l + 1) * 128, xpb, asrc, adst);
        } else {
            finalupd_kernel<<<(N_NODES * 32 + 255) / 256, 256, 0, stream>>>(
                outb, bnsum, bnsum2, gamma + l * 128, beta + l * 128, hA, outp);
        }
    }
}

// Round 13
// 545.532 us; speedup vs baseline: 1.0638x; 1.0290x over previous
//
#include <hip/hip_runtime.h>

// Problem constants (match reference setup_inputs)
constexpr int N_NODES = 50000;
constexpr int N_EDGES = 800000;
constexpr int N_ETOT  = N_EDGES + N_NODES;   // with self loops
constexpr int HID     = 128;
constexpr int HEADS   = 4;
constexpr int ED      = 12;
constexpr int LAYERS  = 4;
constexpr float BN_EPS = 1e-5f;
constexpr int EB = (N_ETOT + 255) / 256;          // 3321 edge blocks
constexpr int GB = (N_NODES + 63) / 64;           // 782 gemm blocks
constexpr int WB = (LAYERS * HID * HID + 255) / 256;  // 256 packW blocks
constexpr int NODE_BLKS = (N_NODES + 3) / 4;          // 12500
// counting-sort CSR build (all-LDS atomics)
constexpr int CHUNK  = 2048;                          // edges per count/scatter block
constexpr int NCHUNK = (N_ETOT + CHUNK - 1) / CHUNK;  // 416
constexpr int NB     = (N_NODES + 127) / 128;         // 391 coarse buckets (dst>>7)
constexpr int F_TOT  = NB * NCHUNK;                   // 162656 flattened (bucket,chunk)
constexpr int SB3    = (F_TOT + 255) / 256;           // 636 scan blocks

typedef __attribute__((ext_vector_type(8))) short short8;
typedef __attribute__((ext_vector_type(4))) float floatx4;

__device__ inline unsigned bf16pair(float a, float b) {
    unsigned ua = __float_as_uint(a), ub = __float_as_uint(b);
    ua = (ua + 0x7FFFu + ((ua >> 16) & 1u)) >> 16;
    ub = (ub + 0x7FFFu + ((ub >> 16) & 1u)) >> 16;
    return ua | (ub << 16);
}

// ---------------------------------------------------------------------------
// pre1: [gemm0 | countA | eamean | packW] — round-5 proven form (f32 Bs,
// 64 rows/block, 52 VGPR). h is kept ONLY in bf16 (hAb) now — the f32 C
// store is gone (residual chain runs in bf16 end-to-end). pre1 attempts that
// FAILED: two-half staging (spill, r3), A-prefetch (null, r6), bf16 Bs
// (null, r10), 32-row grid (regressed, r11) — structural floor; leave it.
// ---------------------------------------------------------------------------
__launch_bounds__(256)
__global__ void pre1_kernel(const int* __restrict__ dst, int* __restrict__ counts,
                            const float* __restrict__ ea, float* __restrict__ easum,
                            const float* __restrict__ W, unsigned short* __restrict__ wb,
                            const float* __restrict__ A, const float* __restrict__ B,
                            const float* __restrict__ bias,
                            unsigned* __restrict__ Cb) {
    __shared__ float smem[64 * 128];   // gemm0 Bs; countA uses NB ints; eamean 12 floats
    int bid = blockIdx.x, t = threadIdx.x;
    if (bid < GB) {
        // ---- gemm0: h = relu(x @ Wp + bp), bf16 out ----
        constexpr int K = 64;
        const float4* B4 = (const float4*)B;
        float4* Bs4 = (float4*)smem;
#pragma unroll
        for (int i = t; i < K * 32; i += 256) Bs4[i] = B4[i];
        __syncthreads();

        int c0 = (t & 15) * 8;
        int r0 = (t >> 4) * 4;
        int rbase = bid * 64 + r0;

        float acc[4][8];
#pragma unroll
        for (int j = 0; j < 4; j++)
#pragma unroll
            for (int c = 0; c < 8; c++) acc[j][c] = 0.f;

        const float4* A4 = (const float4*)A;
        int rg[4];
#pragma unroll
        for (int j = 0; j < 4; j++) rg[j] = min(rbase + j, N_NODES - 1);

        for (int kk = 0; kk < K; kk += 4) {
            float4 av[4];
#pragma unroll
            for (int j = 0; j < 4; j++) av[j] = A4[(size_t)rg[j] * (K / 4) + (kk >> 2)];
            float a_arr[4][4];
#pragma unroll
            for (int j = 0; j < 4; j++) {
                a_arr[j][0] = av[j].x; a_arr[j][1] = av[j].y;
                a_arr[j][2] = av[j].z; a_arr[j][3] = av[j].w;
            }
#pragma unroll
            for (int jj = 0; jj < 4; jj++) {
                float4 b0 = Bs4[(kk + jj) * 32 + (c0 >> 2)];
                float4 b1 = Bs4[(kk + jj) * 32 + (c0 >> 2) + 1];
#pragma unroll
                for (int j = 0; j < 4; j++) {
                    float a = a_arr[j][jj];
                    acc[j][0] += a * b0.x; acc[j][1] += a * b0.y;
                    acc[j][2] += a * b0.z; acc[j][3] += a * b0.w;
                    acc[j][4] += a * b1.x; acc[j][5] += a * b1.y;
                    acc[j][6] += a * b1.z; acc[j][7] += a * b1.w;
                }
            }
        }

#pragma unroll
        for (int j = 0; j < 4; j++) {
            int r = rbase + j;
            if (r < N_NODES) {
                float o[8];
#pragma unroll
                for (int c = 0; c < 8; c++) o[c] = fmaxf(acc[j][c] + bias[c0 + c], 0.f);
                uint4 pk;
                pk.x = bf16pair(o[0], o[1]); pk.y = bf16pair(o[2], o[3]);
                pk.z = bf16pair(o[4], o[5]); pk.w = bf16pair(o[6], o[7]);
                ((uint4*)(Cb + (size_t)r * 64 + (c0 >> 1)))[0] = pk;
            }
        }
    } else if (bid < GB + NCHUNK) {
        // ---- countA: LDS histogram of coarse bucket (dst>>7) for one chunk ----
        int chunk = bid - GB;
        int* lh = (int*)smem;
        for (int i = t; i < NB; i += 256) lh[i] = 0;
        __syncthreads();
        int e0 = chunk * CHUNK;
        int eend = min(e0 + CHUNK, N_ETOT);
        for (int e = e0 + t; e < eend; e += 256) {
            int d = (e < N_EDGES) ? dst[e] : (e - N_EDGES);
            atomicAdd(&lh[d >> 7], 1);
        }
        __syncthreads();
        for (int i = t; i < NB; i += 256) counts[(size_t)chunk * NB + i] = lh[i];
    } else if (bid < GB + NCHUNK + 256) {
        int b2 = bid - GB - NCHUNK;
        float* ls = smem;
        if (t < 12) ls[t] = 0.f;
        __syncthreads();
        float loc[12];
#pragma unroll
        for (int d = 0; d < 12; d++) loc[d] = 0.f;
        for (int e = b2 * 256 + t; e < N_EDGES; e += 256 * 256) {
            const float* er = ea + (size_t)e * ED;
#pragma unroll
            for (int d = 0; d < 12; d++) loc[d] += er[d];
        }
#pragma unroll
        for (int d = 0; d < 12; d++) atomicAdd(&ls[d], loc[d]);
        __syncthreads();
        if (t < 12) atomicAdd(&easum[t], ls[t]);
    } else {
        int idx = (bid - GB - NCHUNK - 256) * 256 + t;
        if (idx < LAYERS * HID * HID) {
            int l = idx >> 14;
            int k = (idx >> 7) & 127;
            int n = idx & 127;
            unsigned u = __float_as_uint(W[idx]);
            u = (u + 0x7FFFu + ((u >> 16) & 1u)) >> 16;
            int kt = k >> 5, q = (k & 31) >> 3, j = k & 7;
            int nt = n >> 4, c = n & 15;
            int lane = q * 16 + c;
            wb[(size_t)l * 16384 + ((size_t)(kt * 8 + nt) * 64 + lane) * 8 + j] =
                (unsigned short)u;
        }
    }
}

// blocksum over flattened (bucket-major) count matrix: j = b*NCHUNK + c,
// stored as counts[c*NB + b].
__global__ void blocksum2_kernel(const int* __restrict__ counts, int* __restrict__ bsum) {
    __shared__ int sd[256];
    int t = threadIdx.x;
    int j = blockIdx.x * 256 + t;
    int v = 0;
    if (j < F_TOT) {
        int bb = j / NCHUNK, cc = j - bb * NCHUNK;
        v = counts[(size_t)cc * NB + bb];
    }
    sd[t] = v;
    __syncthreads();
#pragma unroll
    for (int off = 128; off; off >>= 1) {
        if (t < off) sd[t] += sd[t + off];
        __syncthreads();
    }
    if (t == 0) bsum[blockIdx.x] = sd[0];
}

// ---------------------------------------------------------------------------
// pre2: [bscan | prep] — block 0 scans SB3=636 block sums (3/thread) and
// writes sentinels; block 1 folds We/att_edge.
// ---------------------------------------------------------------------------
__launch_bounds__(256)
__global__ void pre2_kernel(const int* __restrict__ bsum, int* __restrict__ boff,
                            int* __restrict__ chunkbase, int* __restrict__ rowp,
                            const float* __restrict__ easum,
                            const float* __restrict__ We, const float* __restrict__ att_edge,
                            float* __restrict__ wea_all, float* __restrict__ aloop) {
    int t = threadIdx.x;
    if (blockIdx.x == 0) {
        __shared__ int sd[256];
        int b = 3 * t;
        int v0 = (b + 0 < SB3) ? bsum[b + 0] : 0;
        int v1 = (b + 1 < SB3) ? bsum[b + 1] : 0;
        int v2 = (b + 2 < SB3) ? bsum[b + 2] : 0;
        int tot = v0 + v1 + v2;
        sd[t] = tot;
        __syncthreads();
#pragma unroll
        for (int off = 1; off < 256; off <<= 1) {
            int u = (t >= off) ? sd[t - off] : 0;
            __syncthreads();
            sd[t] += u;
            __syncthreads();
        }
        int excl = sd[t] - tot;
        if (b + 0 < SB3) boff[b + 0] = excl;
        if (b + 1 < SB3) boff[b + 1] = excl + v0;
        if (b + 2 < SB3) boff[b + 2] = excl + v0 + v1;
        if (t == 255) {
            chunkbase[F_TOT] = sd[255];    // == N_ETOT
            rowp[N_NODES] = N_ETOT;
        }
    } else {
        __shared__ float em[12];
        __shared__ float weash[LAYERS * ED * HEADS];
        if (t < 12) em[t] = easum[t] / (float)N_EDGES;
        if (t < LAYERS * ED * HEADS) {
            int l = t / (ED * HEADS);
            int r = t % (ED * HEADS);
            int d = r / HEADS;
            int h = r % HEADS;
            float sum = 0.f;
#pragma unroll
            for (int c = 0; c < 32; c++)
                sum += We[((size_t)(l * ED + d)) * HID + h * 32 + c] *
                       att_edge[(l * HEADS + h) * 32 + c];
            wea_all[t] = sum;
            weash[t] = sum;
        }
        __syncthreads();
        if (t < LAYERS * HEADS) {
            int l = t / HEADS, h = t % HEADS;
            float s = 0.f;
#pragma unroll
            for (int d = 0; d < 12; d++) s += em[d] * weash[l * ED * HEADS + d * HEADS + h];
            aloop[t] = s;
        }
    }
}

// add-back: chunkbase[j] = exclusive scan of translated counts
__global__ void addback_kernel(const int* __restrict__ counts, const int* __restrict__ boff,
                               int* __restrict__ chunkbase) {
    __shared__ int sd[256];
    int t = threadIdx.x;
    int j = blockIdx.x * 256 + t;
    int v = 0;
    if (j < F_TOT) {
        int bb = j / NCHUNK, cc = j - bb * NCHUNK;
        v = counts[(size_t)cc * NB + bb];
    }
    sd[t] = v;
    __syncthreads();
#pragma unroll
    for (int off = 1; off < 256; off <<= 1) {
        int u = (t >= off) ? sd[t - off] : 0;
        __syncthreads();
        sd[t] += u;
        __syncthreads();
    }
    if (j < F_TOT) chunkbase[j] = sd[t] - v + boff[blockIdx.x];
}

// ---------------------------------------------------------------------------
// pre3: [xp-proj MFMA (layer 0) | scatterC]. scatterC: LDS-ranked partition
// into coarse-bucket regions; writes are ~NB short contiguous streams/block.
// NOTE: pre3 is the LAST reader of hAb's layer-0 contents; gemm_fused(0)
// overwrites hAb afterwards (residual chain in bf16).
// ---------------------------------------------------------------------------
__launch_bounds__(256)
__global__ void pre3_kernel(const unsigned short* __restrict__ hAb,
                            const unsigned short* __restrict__ wb,
                            const float* __restrict__ att_s, const float* __restrict__ att_d,
                            unsigned* __restrict__ xpb,
                            float* __restrict__ asrc, float* __restrict__ adst,
                            const int* __restrict__ src, const int* __restrict__ dst,
                            const int* __restrict__ chunkbase, int2* __restrict__ bucketed) {
    __shared__ float smem[4 * 16 * 129];   // 33 KB
    int t = threadIdx.x;
    if (blockIdx.x >= GB) {
        int chunk = blockIdx.x - GB;
        int* lb = (int*)smem;       // NB bases
        int* lh = lb + NB;          // NB cursors
        for (int i = t; i < NB; i += 256) {
            lb[i] = chunkbase[(size_t)i * NCHUNK + chunk];
            lh[i] = 0;
        }
        __syncthreads();
        int e0 = chunk * CHUNK;
        int eend = min(e0 + CHUNK, N_ETOT);
        for (int e = e0 + t; e < eend; e += 256) {
            int s, d;
            if (e < N_EDGES) { s = src[e]; d = dst[e]; }
            else             { s = d = e - N_EDGES; }
            int b = d >> 7;
            int lr = atomicAdd(&lh[b], 1);
            bucketed[lb[b] + lr] = make_int2(s, e | ((d & 127) << 20));
        }
        return;
    }
    // ---- plain MFMA projection (layer 0), A from hAb ----
    int bid = blockIdx.x;
    float (*lds)[16][129] = (float (*)[16][129])smem;
    int w = t >> 6, lane = t & 63;
    int rbase = bid * 64 + w * 16;
    int mrow = lane & 15, quad = lane >> 4;

    floatx4 acc[8];
#pragma unroll
    for (int nt = 0; nt < 8; nt++) acc[nt] = (floatx4){0.f, 0.f, 0.f, 0.f};

    int arow = min(rbase + mrow, N_NODES - 1);
    const short8* wb8 = (const short8*)wb;
#pragma unroll
    for (int kt = 0; kt < 4; kt++) {
        short8 afrag = *(const short8*)(hAb + (size_t)arow * 128 + kt * 32 + quad * 8);
#pragma unroll
        for (int nt = 0; nt < 8; nt++) {
            short8 bfrag = wb8[(kt * 8 + nt) * 64 + lane];
            acc[nt] = __builtin_amdgcn_mfma_f32_16x16x32_bf16(afrag, bfrag, acc[nt], 0, 0, 0);
        }
    }
#pragma unroll
    for (int nt = 0; nt < 8; nt++)
#pragma unroll
        for (int rr = 0; rr < 4; rr++)
            lds[w][quad * 4 + rr][nt * 16 + mrow] = acc[nt][rr];

    int row = lane >> 2, h = lane & 3;
    int r = rbase + row;
    float vals[32];
    float ps = 0.f, pd = 0.f;
#pragma unroll
    for (int c = 0; c < 32; c++) {
        float v = lds[w][row][h * 32 + c];
        vals[c] = v;
        ps += v * att_s[h * 32 + c];
        pd += v * att_d[h * 32 + c];
    }
    if (r < N_NODES) {
        unsigned* dstp = xpb + (size_t)r * 64 + h * 16;
#pragma unroll
        for (int qq = 0; qq < 4; qq++) {
            uint4 o;
            o.x = bf16pair(vals[qq * 8 + 0], vals[qq * 8 + 1]);
            o.y = bf16pair(vals[qq * 8 + 2], vals[qq * 8 + 3]);
            o.z = bf16pair(vals[qq * 8 + 4], vals[qq * 8 + 5]);
            o.w = bf16pair(vals[qq * 8 + 6], vals[qq * 8 + 7]);
            ((uint4*)dstp)[qq] = o;
        }
        asrc[r * 4 + h] = ps;
        adst[r * 4 + h] = pd;
    }
}

// ---------------------------------------------------------------------------
// csrd: per-bucket CSR finalize. 128-bin LDS histogram + scan -> rowp; scatter
// bucket edges into final csr + u16 srcs (node reads only srcs: 2B vs 8B).
// ---------------------------------------------------------------------------
__launch_bounds__(256)
__global__ void csrd_kernel(const int2* __restrict__ bucketed, const int* __restrict__ chunkbase,
                            int2* __restrict__ csr, unsigned short* __restrict__ srcs,
                            int* __restrict__ rowp) {
    __shared__ int hist[128], exc[128], cur[128];
    int b = blockIdx.x, t = threadIdx.x;
    int base = chunkbase[(size_t)b * NCHUNK];
    int cend = chunkbase[(size_t)(b + 1) * NCHUNK];
    int cnt = cend - base;
    if (t < 128) { hist[t] = 0; cur[t] = 0; }
    __syncthreads();
    for (int i = t; i < cnt; i += 256)
        atomicAdd(&hist[(bucketed[base + i].y >> 20) & 127], 1);
    __syncthreads();
    if (t < 128) exc[t] = hist[t];
    __syncthreads();
#pragma unroll
    for (int off = 1; off < 128; off <<= 1) {
        int u = (t < 128 && t >= off) ? exc[t - off] : 0;
        __syncthreads();
        if (t < 128) exc[t] += u;
        __syncthreads();
    }
    if (t < 128) {
        exc[t] -= hist[t];   // exclusive
        int node = b * 128 + t;
        if (node < N_NODES) rowp[node] = base + exc[t];
    }
    __syncthreads();
    for (int i = t; i < cnt; i += 256) {
        int2 r = bucketed[base + i];
        int dl = (r.y >> 20) & 127;
        int lr = atomicAdd(&cur[dl], 1);
        int pos = base + exc[dl] + lr;
        csr[pos] = make_int2(r.x, r.y & 0xFFFFF);
        srcs[pos] = (unsigned short)r.x;
    }
}

// ---------------------------------------------------------------------------
// pre4: aedgep — per-edge attention terms for all layers in CSR order (bf16x4).
// ---------------------------------------------------------------------------
__launch_bounds__(256)
__global__ void pre4_kernel(const int2* __restrict__ csr, const float* __restrict__ ea,
                            const float* __restrict__ wea_all, const float* __restrict__ aloop,
                            uint2* __restrict__ aecsr) {
    __shared__ float wsh[LAYERS * ED * HEADS];
    __shared__ float lsh[LAYERS * HEADS];
    int t = threadIdx.x;
    if (t < LAYERS * ED * HEADS) wsh[t] = wea_all[t];
    if (t < LAYERS * HEADS) lsh[t] = aloop[t];
    __syncthreads();
    int i = blockIdx.x * 256 + t;
    if (i >= N_ETOT) return;
    int e = csr[i].y;
    float a[LAYERS][4];
    if (e < N_EDGES) {
        float er[12];
        const float* ep = ea + (size_t)e * ED;
#pragma unroll
        for (int d = 0; d < 12; d++) er[d] = ep[d];
#pragma unroll
        for (int l = 0; l < LAYERS; l++)
#pragma unroll
            for (int h = 0; h < 4; h++) {
                float s = 0.f;
#pragma unroll
                for (int d = 0; d < 12; d++) s += er[d] * wsh[l * 48 + d * 4 + h];
                a[l][h] = s;
            }
    } else {
#pragma unroll
        for (int l = 0; l < LAYERS; l++)
#pragma unroll
            for (int h = 0; h < 4; h++) a[l][h] = lsh[l * 4 + h];
    }
#pragma unroll
    for (int l = 0; l < LAYERS; l++)
        aecsr[(size_t)l * N_ETOT + i] =
            make_uint2(bf16pair(a[l][0], a[l][1]), bf16pair(a[l][2], a[l][3]));
}

// ---------------------------------------------------------------------------
// Fused BN-update + MFMA projection (layers 1..3). outb AND the residual h
// (hAb) are bf16: the pk pack is shared between the hAb store and the MFMA
// A-fragment (stored h == consumed h, bit-exact).
// ---------------------------------------------------------------------------
template <int ADD>
__launch_bounds__(256)
__global__ void gemm_fused_kernel(const unsigned* __restrict__ outb,
                                  const float* __restrict__ bnsum,
                                  const float* __restrict__ bnsum2,
                                  const float* __restrict__ gamma,
                                  const float* __restrict__ beta,
                                  unsigned* __restrict__ hAb,
                                  const unsigned short* __restrict__ wb,
                                  const float* __restrict__ att_s,
                                  const float* __restrict__ att_d,
                                  unsigned* __restrict__ xpb,
                                  float* __restrict__ asrc, float* __restrict__ adst) {
    __shared__ float lds[4][16][129];
    __shared__ float sc_s[128], sh_s[128];
    int t = threadIdx.x;
    if (t < 128) {
        float mu = bnsum[t] / (float)N_NODES;
        float var = bnsum2[t] / (float)N_NODES - mu * mu;
        float inv = rsqrtf(var + BN_EPS);
        float g = gamma[t] * inv;
        sc_s[t] = g;
        sh_s[t] = beta[t] - mu * g;
    }
    __syncthreads();

    int w = t >> 6, lane = t & 63;
    int rbase = blockIdx.x * 64 + w * 16;
    int mrow = lane & 15, quad = lane >> 4;
    int arow = rbase + mrow;
    bool owner = arow < N_NODES;
    int ar = min(arow, N_NODES - 1);

    floatx4 acc[8];
#pragma unroll
    for (int nt = 0; nt < 8; nt++) acc[nt] = (floatx4){0.f, 0.f, 0.f, 0.f};

    const short8* wb8 = (const short8*)wb;
#pragma unroll
    for (int kt = 0; kt < 4; kt++) {
        int cb = kt * 32 + quad * 8;
        uint4 u = *(const uint4*)(outb + (size_t)ar * 64 + (cb >> 1));
        float v[8];
        v[0] = __uint_as_float(u.x << 16);
        v[1] = __uint_as_float(u.x & 0xFFFF0000u);
        v[2] = __uint_as_float(u.y << 16);
        v[3] = __uint_as_float(u.y & 0xFFFF0000u);
        v[4] = __uint_as_float(u.z << 16);
        v[5] = __uint_as_float(u.z & 0xFFFF0000u);
        v[6] = __uint_as_float(u.w << 16);
        v[7] = __uint_as_float(u.w & 0xFFFF0000u);
#pragma unroll
        for (int c = 0; c < 8; c++)
            v[c] = fmaxf(v[c] * sc_s[cb + c] + sh_s[cb + c], 0.f);
        if (ADD) {
            uint4 hu = *(const uint4*)(hAb + (size_t)ar * 64 + (cb >> 1));
            v[0] += __uint_as_float(hu.x << 16);
            v[1] += __uint_as_float(hu.x & 0xFFFF0000u);
            v[2] += __uint_as_float(hu.y << 16);
            v[3] += __uint_as_float(hu.y & 0xFFFF0000u);
            v[4] += __uint_as_float(hu.z << 16);
            v[5] += __uint_as_float(hu.z & 0xFFFF0000u);
            v[6] += __uint_as_float(hu.w << 16);
            v[7] += __uint_as_float(hu.w & 0xFFFF0000u);
        }
        uint4 pk;
        pk.x = bf16pair(v[0], v[1]); pk.y = bf16pair(v[2], v[3]);
        pk.z = bf16pair(v[4], v[5]); pk.w = bf16pair(v[6], v[7]);
        if (owner)
            *(uint4*)(hAb + (size_t)ar * 64 + (cb >> 1)) = pk;
        short8 afrag = *(short8*)&pk;
#pragma unroll
        for (int nt = 0; nt < 8; nt++) {
            short8 bfrag = wb8[(kt * 8 + nt) * 64 + lane];
            acc[nt] = __builtin_amdgcn_mfma_f32_16x16x32_bf16(afrag, bfrag, acc[nt], 0, 0, 0);
        }
    }

#pragma unroll
    for (int nt = 0; nt < 8; nt++)
#pragma unroll
        for (int rr = 0; rr < 4; rr++)
            lds[w][quad * 4 + rr][nt * 16 + mrow] = acc[nt][rr];

    int row = lane >> 2, h = lane & 3;
    int r = rbase + row;
    float vals[32];
    float ps = 0.f, pd = 0.f;
#pragma unroll
    for (int c = 0; c < 32; c++) {
        float v = lds[w][row][h * 32 + c];
        vals[c] = v;
        ps += v * att_s[h * 32 + c];
        pd += v * att_d[h * 32 + c];
    }
    if (r < N_NODES) {
        unsigned* dstp = xpb + (size_t)r * 64 + h * 16;
#pragma unroll
        for (int qq = 0; qq < 4; qq++) {
            uint4 o;
            o.x = bf16pair(vals[qq * 8 + 0], vals[qq * 8 + 1]);
            o.y = bf16pair(vals[qq * 8 + 2], vals[qq * 8 + 3]);
            o.z = bf16pair(vals[qq * 8 + 4], vals[qq * 8 + 5]);
            o.w = bf16pair(vals[qq * 8 + 6], vals[qq * 8 + 7]);
            ((uint4*)dstp)[qq] = o;
        }
        asrc[r * 4 + h] = ps;
        adst[r * 4 + h] = pd;
    }
}

// ---------------------------------------------------------------------------
// Single-pass aggregation, 8-lane subgroups, 16 ch/lane (round-5 structure).
// src via u16 srcs (plain cached loads — NT measured -43us, r9); output bf16.
// ---------------------------------------------------------------------------
__launch_bounds__(256)
__global__ void node_kernel(const uint2* __restrict__ aecsr, const float* __restrict__ asrc,
                            const float* __restrict__ adst, const int* __restrict__ rowp,
                            const unsigned short* __restrict__ srcs,
                            const unsigned* __restrict__ xpb,
                            unsigned* __restrict__ out) {
    int gw = (blockIdx.x * blockDim.x + threadIdx.x) >> 6;
    int lane = threadIdx.x & 63;
    if (gw >= N_NODES) return;
    int sub = lane >> 3;
    int sl  = lane & 7;
    int h   = sl >> 1;
    int beg = rowp[gw], end = rowp[gw + 1];
    const uint4* xp4 = (const uint4*)xpb;
    float adh = adst[gw * 4 + h];

    float a[16];
#pragma unroll
    for (int c = 0; c < 16; c++) a[c] = 0.f;
    float den = 0.f;

#define PROC(JJ)                                                                 \
    {                                                                            \
        int sx = (int)srcs[JJ];                                                  \
        uint2 ae = aecsr[JJ];                                                    \
        unsigned aw = (h & 2) ? ae.y : ae.x;                                     \
        float aeh = __uint_as_float((h & 1) ? (aw & 0xFFFF0000u) : (aw << 16));  \
        float ash = asrc[sx * 4 + h];                                            \
        uint4 v0 = xp4[(size_t)sx * 16 + sl * 2];                                \
        uint4 v1 = xp4[(size_t)sx * 16 + sl * 2 + 1];                            \
        float lg = ash + adh + aeh;                                              \
        lg = (lg > 0.f) ? lg : 0.2f * lg;                                        \
        float ex = __expf(fminf(lg, 60.f));                                      \
        a[0]  += ex * __uint_as_float(v0.x << 16);                               \
        a[1]  += ex * __uint_as_float(v0.x & 0xFFFF0000u);                       \
        a[2]  += ex * __uint_as_float(v0.y << 16);                               \
        a[3]  += ex * __uint_as_float(v0.y & 0xFFFF0000u);                       \
        a[4]  += ex * __uint_as_float(v0.z << 16);                               \
        a[5]  += ex * __uint_as_float(v0.z & 0xFFFF0000u);                       \
        a[6]  += ex * __uint_as_float(v0.w << 16);                               \
        a[7]  += ex * __uint_as_float(v0.w & 0xFFFF0000u);                       \
        a[8]  += ex * __uint_as_float(v1.x << 16);                               \
        a[9]  += ex * __uint_as_float(v1.x & 0xFFFF0000u);                       \
        a[10] += ex * __uint_as_float(v1.y << 16);                               \
        a[11] += ex * __uint_as_float(v1.y & 0xFFFF0000u);                       \
        a[12] += ex * __uint_as_float(v1.z << 16);                               \
        a[13] += ex * __uint_as_float(v1.z & 0xFFFF0000u);                       \
        a[14] += ex * __uint_as_float(v1.w << 16);                               \
        a[15] += ex * __uint_as_float(v1.w & 0xFFFF0000u);                       \
        den += ex;                                                               \
    }

    int j = beg + sub;
    for (; j + 8 < end; j += 16) {
        PROC(j); PROC(j + 8);
    }
    for (; j < end; j += 8) PROC(j);
#undef PROC

#pragma unroll
    for (int c = 0; c < 16; c++) {
        a[c] += __shfl_xor(a[c], 8);
        a[c] += __shfl_xor(a[c], 16);
        a[c] += __shfl_xor(a[c], 32);
    }
    den += __shfl_xor(den, 8);
    den += __shfl_xor(den, 16);
    den += __shfl_xor(den, 32);
    float inv = 1.0f / den;
    if (sub == 0) {
        unsigned* op = out + (size_t)gw * 64 + sl * 8;
        uint4 o0, o1;
        o0.x = bf16pair(a[0] * inv, a[1] * inv);
        o0.y = bf16pair(a[2] * inv, a[3] * inv);
        o0.z = bf16pair(a[4] * inv, a[5] * inv);
        o0.w = bf16pair(a[6] * inv, a[7] * inv);
        o1.x = bf16pair(a[8] * inv, a[9] * inv);
        o1.y = bf16pair(a[10] * inv, a[11] * inv);
        o1.z = bf16pair(a[12] * inv, a[13] * inv);
        o1.w = bf16pair(a[14] * inv, a[15] * inv);
        ((uint4*)op)[0] = o0;
        ((uint4*)op)[1] = o1;
    }
}

// ---------------------------------------------------------------------------
// BatchNorm statistics over bf16 outb (u32-pair loads, 2 ch/thread-word).
// ---------------------------------------------------------------------------
__launch_bounds__(256)
__global__ void bnstats_kernel(const unsigned* __restrict__ hb, float* __restrict__ bnsum,
                               float* __restrict__ bnsum2) {
    __shared__ float ls[4][128], ls2[4][128];
    int t = threadIdx.x;
    int w32 = t & 63, rowoff = t >> 6;
    int r0 = blockIdx.x * 128;
    float s0 = 0.f, s1 = 0.f, q0 = 0.f, q1 = 0.f;
    int rend = min(r0 + 128, N_NODES);
    for (int r = r0 + rowoff; r < rend; r += 4) {
        unsigned u = hb[(size_t)r * 64 + w32];
        float v0 = __uint_as_float(u << 16);
        float v1 = __uint_as_float(u & 0xFFFF0000u);
        s0 += v0; q0 += v0 * v0;
        s1 += v1; q1 += v1 * v1;
    }
    ls[rowoff][w32 * 2 + 0] = s0;  ls[rowoff][w32 * 2 + 1] = s1;
    ls2[rowoff][w32 * 2 + 0] = q0; ls2[rowoff][w32 * 2 + 1] = q1;
    __syncthreads();
    if (t < 128) {
        float s = ls[0][t] + ls[1][t] + ls[2][t] + ls[3][t];
        float q = ls2[0][t] + ls2[1][t] + ls2[2][t] + ls2[3][t];
        atomicAdd(&bnsum[t], s);
        atomicAdd(&bnsum2[t], q);
    }
}

__launch_bounds__(256)
__global__ void finalupd_kernel(const unsigned* __restrict__ outb, const float* __restrict__ bnsum,
                                const float* __restrict__ bnsum2, const float* __restrict__ gamma,
                                const float* __restrict__ beta, const unsigned* __restrict__ hAb,
                                float* __restrict__ dst) {
    __shared__ float sc_s[128], sh_s[128];
    int t = threadIdx.x;
    if (t < 128) {
        float mu = bnsum[t] / (float)N_NODES;
        float var = bnsum2[t] / (float)N_NODES - mu * mu;
        float inv = rsqrtf(var + BN_EPS);
        float g = gamma[t] * inv;
        sc_s[t] = g;
        sh_s[t] = beta[t] - mu * g;
    }
    __syncthreads();
    int i = blockIdx.x * blockDim.x + t;
    if (i >= N_NODES * 32) return;
    int c4 = (i & 31) * 4;
    uint2 u = ((const uint2*)outb)[i];
    uint2 hu = ((const uint2*)hAb)[i];
    float o0 = __uint_as_float(u.x << 16);
    float o1 = __uint_as_float(u.x & 0xFFFF0000u);
    float o2 = __uint_as_float(u.y << 16);
    float o3 = __uint_as_float(u.y & 0xFFFF0000u);
    float h0 = __uint_as_float(hu.x << 16);
    float h1 = __uint_as_float(hu.x & 0xFFFF0000u);
    float h2 = __uint_as_float(hu.y << 16);
    float h3 = __uint_as_float(hu.y & 0xFFFF0000u);
    float4 v;
    v.x = fmaxf(o0 * sc_s[c4 + 0] + sh_s[c4 + 0], 0.f) + h0;
    v.y = fmaxf(o1 * sc_s[c4 + 1] + sh_s[c4 + 1], 0.f) + h1;
    v.z = fmaxf(o2 * sc_s[c4 + 2] + sh_s[c4 + 2], 0.f) + h2;
    v.w = fmaxf(o3 * sc_s[c4 + 3] + sh_s[c4 + 3], 0.f) + h3;
    ((float4*)dst)[i] = v;
}

// ---------------------------------------------------------------------------
extern "C" void kernel_launch(void* const* d_in, const int* in_sizes, int n_in,
                              void* d_out, int out_size, void* d_ws, size_t ws_size,
                              hipStream_t stream) {
    const float* x          = (const float*)d_in[0];
    const int*   edge_index = (const int*)d_in[1];
    const float* edge_attr  = (const float*)d_in[2];
    const float* Wp         = (const float*)d_in[3];
    const float* bp         = (const float*)d_in[4];
    const float* W          = (const float*)d_in[5];
    const float* We         = (const float*)d_in[6];
    const float* att_src    = (const float*)d_in[7];
    const float* att_dst    = (const float*)d_in[8];
    const float* att_edge   = (const float*)d_in[9];
    // d_in[10] bias: absorbed exactly by training-mode BN -> skipped
    const float* gamma      = (const float*)d_in[11];
    const float* beta       = (const float*)d_in[12];
    float* outp = (float*)d_out;

    const int* ei_src = edge_index;
    const int* ei_dst = edge_index + N_EDGES;

    char* p = (char*)d_ws;
    auto alloc = [&](size_t nbytes) {
        char* r = p;
        p += (nbytes + 255) & ~(size_t)255;
        return r;
    };
    // zero-initialized region: easum | bnsum(4 layers x 256)
    float* easum    = (float*)alloc(16 * 4);
    float* bnsumall = (float*)alloc((size_t)LAYERS * 256 * 4);
    size_t zero_bytes = (char*)(bnsumall + LAYERS * 256) - (char*)easum;

    unsigned* hAb   = (unsigned*)alloc((size_t)N_NODES * 64 * 4);   // bf16x2 h (residual chain)
    unsigned* xpb   = (unsigned*)alloc((size_t)N_NODES * 64 * 4);   // bf16x2 gather payload
    unsigned* outb  = (unsigned*)alloc((size_t)N_NODES * 64 * 4);   // bf16x2 aggregation out
    float* asrc     = (float*)alloc((size_t)N_NODES * 4 * 4);
    float* adst     = (float*)alloc((size_t)N_NODES * 4 * 4);
    float* wea_all  = (float*)alloc((LAYERS * 48 + 16) * 4);
    float* aloop    = wea_all + LAYERS * 48;
    unsigned short* wb = (unsigned short*)alloc((size_t)LAYERS * 16384 * 2);
    int* rowp       = (int*)alloc(((size_t)N_NODES + 1) * 4);
    int* counts     = (int*)alloc((size_t)F_TOT * 4);
    int* chunkbase  = (int*)alloc(((size_t)F_TOT + 1) * 4);
    int2* bucketed  = (int2*)alloc((size_t)N_ETOT * 8);
    int2* csr       = (int2*)alloc((size_t)N_ETOT * 8);
    unsigned short* srcs = (unsigned short*)alloc((size_t)N_ETOT * 2);
    uint2* aecsr    = (uint2*)alloc((size_t)LAYERS * N_ETOT * 8);
    int* bsum       = (int*)alloc(1024 * 4);
    int* boff       = (int*)alloc(1024 * 4);

    (void)hipMemsetAsync(easum, 0, zero_bytes, stream);

    // ---- preamble: counting-sort CSR build + folded matrices + W pack + gemm0 ----
    pre1_kernel<<<GB + NCHUNK + 256 + WB, 256, 0, stream>>>(
        ei_dst, counts, edge_attr, easum, W, wb, x, Wp, bp, hAb);
    blocksum2_kernel<<<SB3, 256, 0, stream>>>(counts, bsum);
    pre2_kernel<<<2, 256, 0, stream>>>(bsum, boff, chunkbase, rowp, easum, We, att_edge,
                                       wea_all, aloop);
    addback_kernel<<<SB3, 256, 0, stream>>>(counts, boff, chunkbase);
    pre3_kernel<<<GB + NCHUNK, 256, 0, stream>>>(
        (const unsigned short*)hAb, wb, att_src, att_dst, xpb, asrc, adst,
        ei_src, ei_dst, chunkbase, bucketed);
    csrd_kernel<<<NB, 256, 0, stream>>>(bucketed, chunkbase, csr, srcs, rowp);
    pre4_kernel<<<EB, 256, 0, stream>>>(csr, edge_attr, wea_all, aloop, aecsr);

    for (int l = 0; l < LAYERS; l++) {
        float* bnsum  = bnsumall + l * 256;
        float* bnsum2 = bnsum + 128;
        node_kernel<<<NODE_BLKS, 256, 0, stream>>>(
            aecsr + (size_t)l * N_ETOT, asrc, adst, rowp, srcs, xpb, outb);
        bnstats_kernel<<<(N_NODES + 127) / 128, 256, 0, stream>>>(outb, bnsum, bnsum2);
        if (l < LAYERS - 1) {
            // fused: h_{l+1} = relu(bn_l(outb)) (+ h if l>0) -> hAb, A-frag in-reg
            if (l == 0)
                gemm_fused_kernel<0><<<GB, 256, 0, stream>>>(
                    outb, bnsum, bnsum2, gamma + l * 128, beta + l * 128, hAb,
                    wb + (size_t)(l + 1) * 16384, att_src + (l + 1) * 128,
                    att_dst + (l + 1) * 128, xpb, asrc, adst);
            else
                gemm_fused_kernel<1><<<GB, 256, 0, stream>>>(
                    outb, bnsum, bnsum2, gamma + l * 128, beta + l * 128, hAb,
                    wb + (size_t)(l + 1) * 16384, att_src + (l + 1) * 128,
                    att_dst + (l + 1) * 128, xpb, asrc, adst);
        } else {
            finalupd_kernel<<<(N_NODES * 32 + 255) / 256, 256, 0, stream>>>(
                outb, bnsum, bnsum2, gamma + l * 128, beta + l * 128, hAb, outp);
        }
    }
}